// Round 10
// baseline (177.314 us; speedup 1.0000x reference)
//
#include <hip/hip_runtime.h>
#include <hip/hip_fp8.h>

#define NEG 0.2f
#define BSZ 224          // nodes per dst bucket
#define MAXBUK 512       // >= ceil(N/BSZ) = 447
#define NBIN 512         // binning blocks
#define CAP 16384        // slab capacity per bucket (max padded load ~15K at E=3.2M)

typedef float v2f __attribute__((ext_vector_type(2)));

__device__ __forceinline__ float elufast(float x){ return x > 0.0f ? x : __expf(x) - 1.0f; }
__device__ __forceinline__ float b2f(unsigned short b){ return __uint_as_float((unsigned)b << 16); }
__device__ __forceinline__ unsigned short f2b(float x){
    unsigned u = __float_as_uint(x);
    return (unsigned short)((u + 0x7FFFu + ((u >> 16) & 1u)) >> 16);   // RNE
}

// decode 8 fp8-e4m3 (uint2) via HW v_cvt_pk_f32_fp8, accumulate with packed fma (v_pk_fma_f32)
__device__ __forceinline__ void fma8(uint2 r, float w, v2f* acc){
    v2f w2 = {w, w};
    v2f f0 = __builtin_amdgcn_cvt_pk_f32_fp8(r.x, false);
    v2f f1 = __builtin_amdgcn_cvt_pk_f32_fp8(r.x, true);
    v2f f2 = __builtin_amdgcn_cvt_pk_f32_fp8(r.y, false);
    v2f f3 = __builtin_amdgcn_cvt_pk_f32_fp8(r.y, true);
    acc[0] = __builtin_elementwise_fma(f0, w2, acc[0]);
    acc[1] = __builtin_elementwise_fma(f1, w2, acc[1]);
    acc[2] = __builtin_elementwise_fma(f2, w2, acc[2]);
    acc[3] = __builtin_elementwise_fma(f3, w2, acc[3]);
}

// ---- layer 1 node transform (packed v2f): xw1(fp8)[N,64], asvb(bf16x4)[N], adv[N,4] ----
__global__ void k_l1_node(const float* __restrict__ x, const float* __restrict__ W1,
                          const float* __restrict__ as1, const float* __restrict__ ad1,
                          unsigned char* __restrict__ xw1, uint2* __restrict__ asvb,
                          float* __restrict__ adv, int N){
    __shared__ float sW[256], sA[64], sD[64];
    int tid = threadIdx.x;
    sW[tid] = W1[tid];
    if (tid < 64){ sA[tid] = as1[tid]; sD[tid] = ad1[tid]; }
    __syncthreads();
    int i = blockIdx.x * 256 + tid;
    if (i >= N) return;
    float4 xv = ((const float4*)x)[i];
    const v2f* sW0 = (const v2f*)sW;
    const v2f* sW1v = (const v2f*)(sW + 64);
    const v2f* sW2v = (const v2f*)(sW + 128);
    const v2f* sW3v = (const v2f*)(sW + 192);
    v2f xx = {xv.x, xv.x}, yy = {xv.y, xv.y}, zz = {xv.z, xv.z}, ww = {xv.w, xv.w};
    v2f xwv[32];
    #pragma unroll
    for (int j = 0; j < 32; j++){
        v2f t = xx * sW0[j];
        t = __builtin_elementwise_fma(yy, sW1v[j], t);
        t = __builtin_elementwise_fma(zz, sW2v[j], t);
        t = __builtin_elementwise_fma(ww, sW3v[j], t);
        xwv[j] = t;
    }
    unsigned wv[16];
    #pragma unroll
    for (int j = 0; j < 16; j++){
        unsigned p = 0;
        p = __builtin_amdgcn_cvt_pk_fp8_f32(xwv[2 * j].x,     xwv[2 * j].y,     p, false);
        p = __builtin_amdgcn_cvt_pk_fp8_f32(xwv[2 * j + 1].x, xwv[2 * j + 1].y, p, true);
        wv[j] = p;
    }
    uint4* dp = (uint4*)(xw1 + (size_t)i * 64);
    dp[0] = make_uint4(wv[0],  wv[1],  wv[2],  wv[3]);
    dp[1] = make_uint4(wv[4],  wv[5],  wv[6],  wv[7]);
    dp[2] = make_uint4(wv[8],  wv[9],  wv[10], wv[11]);
    dp[3] = make_uint4(wv[12], wv[13], wv[14], wv[15]);
    const v2f* sAv = (const v2f*)sA;
    const v2f* sDv = (const v2f*)sD;
    float al[4];
    #pragma unroll
    for (int h = 0; h < 4; h++){
        v2f asv = {0.f, 0.f}, adw = {0.f, 0.f};
        #pragma unroll
        for (int c2 = 0; c2 < 8; c2++){
            asv = __builtin_elementwise_fma(xwv[h * 8 + c2], sAv[h * 8 + c2], asv);
            adw = __builtin_elementwise_fma(xwv[h * 8 + c2], sDv[h * 8 + c2], adw);
        }
        al[h] = asv.x + asv.y;
        adv[i * 4 + h] = adw.x + adw.y;
    }
    asvb[i] = make_uint2((unsigned)f2b(al[0]) | ((unsigned)f2b(al[1]) << 16),
                         (unsigned)f2b(al[2]) | ((unsigned)f2b(al[3]) << 16));
}

// ---- single-pass slab binning, 64B-aligned block-exclusive reservations ----
// staged slab for bucket b: [b*CAP, b*CAP + gcnt[b]); pad gaps = 0xFFFFFFFF sentinel
__global__ void k_bin2(const int* __restrict__ src, const int* __restrict__ dst,
                       int* __restrict__ gcnt, unsigned* __restrict__ staged,
                       int E, int chunksz, int nbuk){
    __shared__ int hist[MAXBUK];
    __shared__ int cur[MAXBUK];
    __shared__ int pend[MAXBUK];
    int tid = threadIdx.x;
    for (int b = tid; b < nbuk; b += 1024) hist[b] = 0;
    __syncthreads();
    int e0 = blockIdx.x * chunksz, e1 = min(E, e0 + chunksz);
    for (int e = e0 + tid; e < e1; e += 1024)
        atomicAdd(&hist[(unsigned)dst[e] / BSZ], 1);     // pass 1
    __syncthreads();
    for (int b = tid; b < nbuk; b += 1024){
        int cnt = hist[b];
        int padded = (cnt + 15) & ~15;                   // multiple of 16 edges = 64B
        int base = b * CAP + (padded ? atomicAdd(&gcnt[b], padded) : 0);
        cur[b] = base;                                   // 64B-aligned, line-exclusive
        pend[b] = base + padded;
    }
    __syncthreads();
    for (int e = e0 + tid; e < e1; e += 1024){           // pass 2: scatter (own lines only)
        int d = dst[e];
        int buk = (unsigned)d / BSZ;
        int pos = atomicAdd(&cur[buk], 1);
        staged[pos] = (unsigned)src[e] | ((unsigned)(d - buk * BSZ) << 17);
    }
    __syncthreads();
    for (int b = tid; b < nbuk; b += 1024)               // sentinel-fill pad tails
        for (int p = cur[b]; p < pend[b]; p++) staged[p] = 0xFFFFFFFFu;
}

// ---- per-bucket local sort (1024 threads): skip sentinels, per-dst (start,end), csr ----
__global__ void k_local(const unsigned* __restrict__ staged, const int* __restrict__ gcnt,
                        int2* __restrict__ offp, int* __restrict__ csr, int N){
    __shared__ int deg[BSZ];
    __shared__ int cur[BSZ];
    __shared__ int ts[256];
    int b = blockIdx.x, t = threadIdx.x;
    int lo = b * BSZ, hi = min(N, lo + BSZ);
    int e0 = b * CAP, e1 = e0 + gcnt[b];
    if (t < BSZ) deg[t] = 0;
    __syncthreads();
    for (int e = e0 + t; e < e1; e += 1024){
        unsigned se = staged[e];
        if (se != 0xFFFFFFFFu) atomicAdd(&deg[se >> 17], 1);
    }
    __syncthreads();
    int v = 0;
    if (t < 256){
        v = (t < BSZ) ? deg[t] : 0;
        ts[t] = v;
    }
    __syncthreads();
    for (int s = 1; s < 256; s <<= 1){            // 256-lane Hillis-Steele; others barrier-only
        int tmp = (t >= s && t < 256) ? ts[t - s] : 0;
        __syncthreads();
        if (t < 256) ts[t] += tmp;
        __syncthreads();
    }
    if (t < BSZ){
        cur[t] = e0 + ts[t] - v;
        if (lo + t < hi) offp[lo + t] = make_int2(e0 + ts[t] - v, e0 + ts[t]);
    }
    __syncthreads();
    for (int e = e0 + t; e < e1; e += 1024){
        unsigned se = staged[e];
        if (se == 0xFFFFFFFFu) continue;
        int pos = atomicAdd(&cur[se >> 17], 1);
        csr[pos] = (int)(se & 0x1FFFFu);
    }
}

// ---- layer 1 gather: 4-deep batch + fold-reduce + distributed epilogue ----
// wave per dst; lane = (edge slot g=lane>>3, chan oct q=lane&7), head h=q>>1.
__global__ void k_l1_gather(const int2* __restrict__ offp, const int* __restrict__ csr,
                            const uint2* __restrict__ asvb, const float* __restrict__ adv,
                            const unsigned char* __restrict__ xw1, const float* __restrict__ b1,
                            unsigned char* __restrict__ h1f8, int N){
    int tid = threadIdx.x;
    int wid = (int)(((long)blockIdx.x * 256 + tid) >> 6);
    if (wid >= N) return;
    int lane = tid & 63;
    int g = lane >> 3;          // edge slot 0..7
    int q = lane & 7;           // channel oct: channels q*8 .. q*8+7
    int h = q >> 1;             // head
    float advd = adv[wid * 4 + h];
    const unsigned char* xwq = xw1 + q * 8;                 // per-lane row base
    const char* asvbh = (const char*)asvb + h * 2;          // per-lane bf16 slot

    v2f acc2[4] = {{0.f, 0.f}, {0.f, 0.f}, {0.f, 0.f}, {0.f, 0.f}};
    float den = 0.f;
    int2 rng = offp[wid];
    int k = rng.x, end = rng.y;
    for (; k + 32 <= end; k += 32){         // 4 batches of 8 edges: all loads in flight
        int s0 = csr[k + g];
        int s1 = csr[k + 8 + g];
        int s2 = csr[k + 16 + g];
        int s3 = csr[k + 24 + g];
        uint2 r0 = *(const uint2*)(xwq + ((size_t)s0 << 6));
        uint2 r1 = *(const uint2*)(xwq + ((size_t)s1 << 6));
        uint2 r2 = *(const uint2*)(xwq + ((size_t)s2 << 6));
        uint2 r3 = *(const uint2*)(xwq + ((size_t)s3 << 6));
        float a0 = b2f(*(const unsigned short*)(asvbh + ((size_t)s0 << 3)));
        float a1 = b2f(*(const unsigned short*)(asvbh + ((size_t)s1 << 3)));
        float a2 = b2f(*(const unsigned short*)(asvbh + ((size_t)s2 << 3)));
        float a3 = b2f(*(const unsigned short*)(asvbh + ((size_t)s3 << 3)));
        float t0 = a0 + advd, t1 = a1 + advd, t2 = a2 + advd, t3 = a3 + advd;
        float w0 = __expf(fmaxf(t0, NEG * t0));
        float w1 = __expf(fmaxf(t1, NEG * t1));
        float w2 = __expf(fmaxf(t2, NEG * t2));
        float w3 = __expf(fmaxf(t3, NEG * t3));
        den += (w0 + w1) + (w2 + w3);
        fma8(r0, w0, acc2);
        fma8(r1, w1, acc2);
        fma8(r2, w2, acc2);
        fma8(r3, w3, acc2);
    }
    if (k + 16 <= end){                     // 2-batch step
        int sA = csr[k + g];
        int sB = csr[k + 8 + g];
        uint2 rA = *(const uint2*)(xwq + ((size_t)sA << 6));
        uint2 rB = *(const uint2*)(xwq + ((size_t)sB << 6));
        float aA = b2f(*(const unsigned short*)(asvbh + ((size_t)sA << 3)));
        float aB = b2f(*(const unsigned short*)(asvbh + ((size_t)sB << 3)));
        float tA = aA + advd, tB = aB + advd;
        float wA = __expf(fmaxf(tA, NEG * tA));
        float wB = __expf(fmaxf(tB, NEG * tB));
        den += wA + wB;
        fma8(rA, wA, acc2);
        fma8(rB, wB, acc2);
        k += 16;
    }
    for (; k < end; k += 8){                // masked tail
        int e = k + g;
        bool valid = e < end;
        int s = csr[valid ? e : end - 1];
        uint2 r = *(const uint2*)(xwq + ((size_t)s << 6));
        float a = b2f(*(const unsigned short*)(asvbh + ((size_t)s << 3)));
        float t = a + advd;
        float w = valid ? __expf(fmaxf(t, NEG * t)) : 0.f;
        den += w;
        fma8(r, w, acc2);
    }

    // ---- fold-reduce across the 8 edge slots (lane bits 3..5), keep-half per stage ----
    v2f t0, t1, t2, t3;
    t0.x = __shfl_xor(acc2[0].x, 32); t0.y = __shfl_xor(acc2[0].y, 32);
    t1.x = __shfl_xor(acc2[1].x, 32); t1.y = __shfl_xor(acc2[1].y, 32);
    t2.x = __shfl_xor(acc2[2].x, 32); t2.y = __shfl_xor(acc2[2].y, 32);
    t3.x = __shfl_xor(acc2[3].x, 32); t3.y = __shfl_xor(acc2[3].y, 32);
    bool gb2 = (lane & 32) != 0;                 // g bit2
    v2f n0 = gb2 ? (acc2[2] + t2) : (acc2[0] + t0);   // keep half holding my channel pair
    v2f n1 = gb2 ? (acc2[3] + t3) : (acc2[1] + t1);
    v2f u0, u1;
    u0.x = __shfl_xor(n0.x, 16); u0.y = __shfl_xor(n0.y, 16);
    u1.x = __shfl_xor(n1.x, 16); u1.y = __shfl_xor(n1.y, 16);
    bool gb1 = (lane & 16) != 0;                 // g bit1
    v2f rr = gb1 ? (n1 + u1) : (n0 + u0);
    v2f z;
    z.x = __shfl_xor(rr.x, 8); z.y = __shfl_xor(rr.y, 8);
    rr += z;                                     // summed over all 8 slots
    bool gb0 = (lane & 8) != 0;                  // g bit0 -> component
    den += __shfl_xor(den, 8);
    den += __shfl_xor(den, 16);
    den += __shfl_xor(den, 32);
    float val = gb0 ? rr.y : rr.x;               // total for channel c = q*8+g

    // ---- distributed epilogue: all 64 lanes; lane (g,q) owns channel c=q*8+g ----
    int c = q * 8 + g;
    float aself = b2f(*(const unsigned short*)(asvbh + ((size_t)wid << 3)));
    float tsv = aself + advd;
    float ws = __expf(fmaxf(tsv, NEG * tsv));               // self-loop weight (per head)
    unsigned selfb = xw1[(size_t)wid * 64 + c];             // coalesced byte load
    v2f sf = __builtin_amdgcn_cvt_pk_f32_fp8(selfb, false); // sf.x = fp8(byte0)
    float asel = val + ws * sf.x;
    float inv = 1.0f / (den + ws + 1e-16f);
    float o = elufast(asel * inv + b1[c]);
    unsigned p = __builtin_amdgcn_cvt_pk_fp8_f32(o, o, 0, false);
    h1f8[(size_t)wid * 64 + c] = (unsigned char)p;          // coalesced byte store
}

// ---- layer 2 node transform (packed v2f + b64 LDS reads): xw2[N,8], adv2[N,4] ----
__global__ void k_l2_node(const unsigned char* __restrict__ h1f8, const float* __restrict__ W2,
                          const float* __restrict__ ad2, float* __restrict__ xw2,
                          float* __restrict__ adv2, int N){
    __shared__ float sW[512], sD[8];
    int tid = threadIdx.x;
    sW[tid] = W2[tid];
    sW[256 + tid] = W2[256 + tid];
    if (tid < 8) sD[tid] = ad2[tid];
    __syncthreads();
    int i = blockIdx.x * 256 + tid;
    if (i >= N) return;
    const uint2* rp = (const uint2*)(h1f8 + (size_t)i * 64);
    v2f acc2[4] = {{0.f, 0.f}, {0.f, 0.f}, {0.f, 0.f}, {0.f, 0.f}};
    #pragma unroll
    for (int b8 = 0; b8 < 8; b8++){
        uint2 r = rp[b8];
        v2f f0 = __builtin_amdgcn_cvt_pk_f32_fp8(r.x, false);
        v2f f1 = __builtin_amdgcn_cvt_pk_f32_fp8(r.x, true);
        v2f f2 = __builtin_amdgcn_cvt_pk_f32_fp8(r.y, false);
        v2f f3 = __builtin_amdgcn_cvt_pk_f32_fp8(r.y, true);
        float f[8] = {f0.x, f0.y, f1.x, f1.y, f2.x, f2.y, f3.x, f3.y};
        #pragma unroll
        for (int j = 0; j < 8; j++){
            v2f hcv = {f[j], f[j]};
            const v2f* wrow = (const v2f*)&sW[(b8 * 8 + j) * 8];   // broadcast b64 reads
            acc2[0] = __builtin_elementwise_fma(hcv, wrow[0], acc2[0]);
            acc2[1] = __builtin_elementwise_fma(hcv, wrow[1], acc2[1]);
            acc2[2] = __builtin_elementwise_fma(hcv, wrow[2], acc2[2]);
            acc2[3] = __builtin_elementwise_fma(hcv, wrow[3], acc2[3]);
        }
    }
    float4* xo = (float4*)(xw2 + (size_t)i * 8);
    xo[0] = make_float4(acc2[0].x, acc2[0].y, acc2[1].x, acc2[1].y);
    xo[1] = make_float4(acc2[2].x, acc2[2].y, acc2[3].x, acc2[3].y);
    float4 dv;
    dv.x = acc2[0].x * sD[0] + acc2[0].y * sD[1];
    dv.y = acc2[1].x * sD[2] + acc2[1].y * sD[3];
    dv.z = acc2[2].x * sD[4] + acc2[2].y * sD[5];
    dv.w = acc2[3].x * sD[6] + acc2[3].y * sD[7];
    *(float4*)(adv2 + (size_t)i * 4) = dv;
}

// ---- layer 2 gather: lane = (edge slot g=lane>>2 0..15, head hh=lane&3) ----
__global__ void k_l2_gather(const int2* __restrict__ offp, const int* __restrict__ csr,
                            const float* __restrict__ adv2, const float* __restrict__ xw2,
                            const float* __restrict__ b2, const float* __restrict__ as2,
                            float* __restrict__ pool, int N){
    __shared__ float lpool[8];
    int tid = threadIdx.x;
    if (tid < 8) lpool[tid] = 0.f;
    __syncthreads();
    int wid = (int)(((long)blockIdx.x * 256 + tid) >> 6);
    if (wid < N){
        int lane = tid & 63;
        int g = lane >> 2;          // edge slot 0..15
        int hh = lane & 3;          // head
        float2 a2h = *(const float2*)&as2[hh * 2];
        float advd = adv2[wid * 4 + hh];
        const char* xwh = (const char*)xw2 + hh * 8;
        v2f accv = {0.f, 0.f};
        float den = 0.f;

        auto edge = [&](int s, bool valid){
            v2f v = *(const v2f*)(xwh + ((size_t)s << 5));
            float al = v.x * a2h.x + v.y * a2h.y;
            float t = al + advd;
            float w = valid ? __expf(fmaxf(t, NEG * t)) : 0.f;
            den += w;
            v2f w2 = {w, w};
            accv = __builtin_elementwise_fma(v, w2, accv);
        };

        int2 rng = offp[wid];
        int k = rng.x, end = rng.y;
        for (; k + 32 <= end; k += 32){     // 2 batches of 16 edges in flight
            int s0 = csr[k + g], s1 = csr[k + 16 + g];
            edge(s0, true); edge(s1, true);
        }
        for (; k < end; k += 16){           // masked tail
            int e = k + g;
            bool valid = e < end;
            int s = csr[valid ? e : end - 1];
            edge(s, valid);
        }
        // reduce over edge slots (lane bits 2..5)
        #pragma unroll
        for (int m = 4; m <= 32; m <<= 1){
            accv.x += __shfl_xor(accv.x, m);
            accv.y += __shfl_xor(accv.y, m);
            den    += __shfl_xor(den, m);
        }
        if (g == 0){                         // lanes 0..3, lane hh owns head hh
            v2f v = *(const v2f*)(xwh + ((size_t)wid << 5));
            float al = v.x * a2h.x + v.y * a2h.y;
            float t = al + advd;
            float ws = __expf(fmaxf(t, NEG * t));
            den += ws;
            accv.x += ws * v.x;
            accv.y += ws * v.y;
            float inv = 1.0f / (den + 1e-16f);
            float o0 = elufast(accv.x * inv + b2[hh * 2]);
            float o1 = elufast(accv.y * inv + b2[hh * 2 + 1]);
            atomicAdd(&lpool[hh * 2], o0);
            atomicAdd(&lpool[hh * 2 + 1], o1);
        }
    }
    __syncthreads();
    if (tid < 8) atomicAdd(&pool[(blockIdx.x & 63) * 8 + tid], lpool[tid]);
}

// ---- output head: reduce 64x8 pool partials, apply mean+W+sigmoid ----
__global__ void k_final(const float* __restrict__ pool, const float* __restrict__ Wout,
                        const float* __restrict__ bout, float* __restrict__ out, float invN){
    int lane = threadIdx.x;      // 64 lanes, lane l owns slot l
    const float4* p4 = (const float4*)(pool + lane * 8);
    float4 a = p4[0], b = p4[1];
    float v[8] = {a.x, a.y, a.z, a.w, b.x, b.y, b.z, b.w};
    #pragma unroll
    for (int m = 1; m <= 32; m <<= 1){
        #pragma unroll
        for (int j = 0; j < 8; j++) v[j] += __shfl_xor(v[j], m);
    }
    if (lane == 0){
        float z = bout[0];
        #pragma unroll
        for (int j = 0; j < 8; j++) z += v[j] * invN * Wout[j];
        out[0] = 1.0f / (1.0f + __expf(-z));
    }
}

extern "C" void kernel_launch(void* const* d_in, const int* in_sizes, int n_in,
                              void* d_out, int out_size, void* d_ws, size_t ws_size,
                              hipStream_t stream){
    const float* x    = (const float*)d_in[0];
    const int*   ei   = (const int*)d_in[1];     // int32
    const float* W1   = (const float*)d_in[2];
    const float* as1  = (const float*)d_in[3];
    const float* ad1  = (const float*)d_in[4];
    const float* b1   = (const float*)d_in[5];
    const float* W2   = (const float*)d_in[6];
    const float* as2  = (const float*)d_in[7];
    const float* ad2  = (const float*)d_in[8];
    const float* b2   = (const float*)d_in[9];
    const float* Wout = (const float*)d_in[10];
    const float* bout = (const float*)d_in[11];
    float* out = (float*)d_out;

    int N = in_sizes[0] / 4;
    int E = in_sizes[1] / 2;
    const int* src = ei;
    const int* dst = ei + E;

    char* ws = (char*)d_ws;
    size_t off_b = 0;
    auto alloc = [&](size_t bytes)->void*{
        void* p = ws + off_b;
        off_b += (bytes + 255) & ~(size_t)255;
        return p;
    };
    unsigned char* xw1  = (unsigned char*)alloc((size_t)N * 64);  // fp8 e4m3
    unsigned char* h1f8 = (unsigned char*)alloc((size_t)N * 64);  // fp8 e4m3 h1
    uint2*    asvb   = (uint2*)alloc((size_t)N * 8);              // bf16x4 alpha_src
    float*    adv    = (float*)alloc((size_t)N * 4 * 4);
    float*    adv2   = (float*)alloc((size_t)N * 4 * 4);
    int*      gcnt   = (int*)alloc((size_t)MAXBUK * 4);           // per-bucket fill count
    unsigned* staged = (unsigned*)alloc((size_t)MAXBUK * CAP * 4);// slab: src | localdst<<17
    int2*     offp   = (int2*)alloc((size_t)N * 8);               // per-dst (start,end)
    int*      csr    = (int*)alloc((size_t)MAXBUK * CAP * 4);     // slab csr
    float*    xw2    = (float*)alloc((size_t)N * 8 * 4);
    float*    pool   = (float*)alloc(64 * 8 * 4);

    int nbuk = (N + BSZ - 1) / BSZ;          // 447
    int chunksz = (E + NBIN - 1) / NBIN;

    hipMemsetAsync(pool, 0, 64 * 8 * 4, stream);
    hipMemsetAsync(gcnt, 0, (size_t)MAXBUK * 4, stream);

    // single-pass slab binning (line-exclusive reservations) + per-bucket local sort
    k_bin2<<<NBIN, 1024, 0, stream>>>(src, dst, gcnt, staged, E, chunksz, nbuk);
    k_l1_node<<<(N + 255) / 256, 256, 0, stream>>>(x, W1, as1, ad1, xw1, asvb, adv, N);
    k_local<<<nbuk, 1024, 0, stream>>>(staged, gcnt, offp, csr, N);

    // layer 1 gather (4-deep batch + fold-reduce + distributed epilogue -> h1 fp8)
    k_l1_gather<<<(int)(((long)N * 64 + 255) / 256), 256, 0, stream>>>(
        offp, csr, asvb, adv, xw1, b1, h1f8, N);
    // dense layer-2 node transform (packed)
    k_l2_node<<<(N + 255) / 256, 256, 0, stream>>>(h1f8, W2, ad2, xw2, adv2, N);
    // layer 2 gather + fused mean pool
    k_l2_gather<<<(int)(((long)N * 64 + 255) / 256), 256, 0, stream>>>(
        offp, csr, adv2, xw2, b2, as2, pool, N);
    // head
    k_final<<<1, 64, 0, stream>>>(pool, Wout, bout, out, 1.0f / (float)N);
}

// Round 11
// 168.414 us; speedup vs baseline: 1.0528x; 1.0528x over previous
//
#include <hip/hip_runtime.h>
#include <hip/hip_fp8.h>

#define NEG 0.2f
#define BSZ 224          // nodes per dst bucket
#define MAXBUK 512       // >= ceil(N/BSZ) = 447
#define NBIN 512         // binning blocks
#define CAP 16384        // slab capacity per bucket (max padded load ~10K at E=3.2M)
#define LSTG 6400        // LDS staging entries (>= chunksz = ceil(E/NBIN) = 6250)

typedef float v2f __attribute__((ext_vector_type(2)));

__device__ __forceinline__ float elufast(float x){ return x > 0.0f ? x : __expf(x) - 1.0f; }
__device__ __forceinline__ float b2f(unsigned short b){ return __uint_as_float((unsigned)b << 16); }
__device__ __forceinline__ unsigned short f2b(float x){
    unsigned u = __float_as_uint(x);
    return (unsigned short)((u + 0x7FFFu + ((u >> 16) & 1u)) >> 16);   // RNE
}

// decode 8 fp8-e4m3 (uint2) via HW v_cvt_pk_f32_fp8, accumulate with packed fma (v_pk_fma_f32)
__device__ __forceinline__ void fma8(uint2 r, float w, v2f* acc){
    v2f w2 = {w, w};
    v2f f0 = __builtin_amdgcn_cvt_pk_f32_fp8(r.x, false);
    v2f f1 = __builtin_amdgcn_cvt_pk_f32_fp8(r.x, true);
    v2f f2 = __builtin_amdgcn_cvt_pk_f32_fp8(r.y, false);
    v2f f3 = __builtin_amdgcn_cvt_pk_f32_fp8(r.y, true);
    acc[0] = __builtin_elementwise_fma(f0, w2, acc[0]);
    acc[1] = __builtin_elementwise_fma(f1, w2, acc[1]);
    acc[2] = __builtin_elementwise_fma(f2, w2, acc[2]);
    acc[3] = __builtin_elementwise_fma(f3, w2, acc[3]);
}

// ---- layer 1 node transform (packed v2f): xw1(fp8)[N,64], asvb(bf16x4)[N], adv[N,4] ----
__global__ void k_l1_node(const float* __restrict__ x, const float* __restrict__ W1,
                          const float* __restrict__ as1, const float* __restrict__ ad1,
                          unsigned char* __restrict__ xw1, uint2* __restrict__ asvb,
                          float* __restrict__ adv, int N){
    __shared__ float sW[256], sA[64], sD[64];
    int tid = threadIdx.x;
    sW[tid] = W1[tid];
    if (tid < 64){ sA[tid] = as1[tid]; sD[tid] = ad1[tid]; }
    __syncthreads();
    int i = blockIdx.x * 256 + tid;
    if (i >= N) return;
    float4 xv = ((const float4*)x)[i];
    const v2f* sW0 = (const v2f*)sW;
    const v2f* sW1v = (const v2f*)(sW + 64);
    const v2f* sW2v = (const v2f*)(sW + 128);
    const v2f* sW3v = (const v2f*)(sW + 192);
    v2f xx = {xv.x, xv.x}, yy = {xv.y, xv.y}, zz = {xv.z, xv.z}, ww = {xv.w, xv.w};
    v2f xwv[32];
    #pragma unroll
    for (int j = 0; j < 32; j++){
        v2f t = xx * sW0[j];
        t = __builtin_elementwise_fma(yy, sW1v[j], t);
        t = __builtin_elementwise_fma(zz, sW2v[j], t);
        t = __builtin_elementwise_fma(ww, sW3v[j], t);
        xwv[j] = t;
    }
    unsigned wv[16];
    #pragma unroll
    for (int j = 0; j < 16; j++){
        unsigned p = 0;
        p = __builtin_amdgcn_cvt_pk_fp8_f32(xwv[2 * j].x,     xwv[2 * j].y,     p, false);
        p = __builtin_amdgcn_cvt_pk_fp8_f32(xwv[2 * j + 1].x, xwv[2 * j + 1].y, p, true);
        wv[j] = p;
    }
    uint4* dp = (uint4*)(xw1 + (size_t)i * 64);
    dp[0] = make_uint4(wv[0],  wv[1],  wv[2],  wv[3]);
    dp[1] = make_uint4(wv[4],  wv[5],  wv[6],  wv[7]);
    dp[2] = make_uint4(wv[8],  wv[9],  wv[10], wv[11]);
    dp[3] = make_uint4(wv[12], wv[13], wv[14], wv[15]);
    const v2f* sAv = (const v2f*)sA;
    const v2f* sDv = (const v2f*)sD;
    float al[4];
    #pragma unroll
    for (int h = 0; h < 4; h++){
        v2f asv = {0.f, 0.f}, adw = {0.f, 0.f};
        #pragma unroll
        for (int c2 = 0; c2 < 8; c2++){
            asv = __builtin_elementwise_fma(xwv[h * 8 + c2], sAv[h * 8 + c2], asv);
            adw = __builtin_elementwise_fma(xwv[h * 8 + c2], sDv[h * 8 + c2], adw);
        }
        al[h] = asv.x + asv.y;
        adv[i * 4 + h] = adw.x + adw.y;
    }
    asvb[i] = make_uint2((unsigned)f2b(al[0]) | ((unsigned)f2b(al[1]) << 16),
                         (unsigned)f2b(al[2]) | ((unsigned)f2b(al[3]) << 16));
}

// ---- slab binning with LDS staging: scatter to LDS, flush full-line bursts ----
// staged slab for bucket b: [b*CAP, b*CAP + gcnt[b]); pad gaps = 0xFFFFFFFF sentinel
__global__ void k_bin2(const int* __restrict__ src, const int* __restrict__ dst,
                       int* __restrict__ gcnt, unsigned* __restrict__ staged,
                       int E, int chunksz, int nbuk){
    __shared__ int hist[MAXBUK];
    __shared__ int cur[MAXBUK];     // LDS insert cursor
    __shared__ int lsb[MAXBUK];     // local start in lstg
    __shared__ int gbase[MAXBUK];   // reserved global base (64B aligned)
    __shared__ int ts[512];
    __shared__ unsigned lstg[LSTG]; // block-local sorted edges (~25 KB)
    int tid = threadIdx.x;
    for (int b = tid; b < MAXBUK; b += 1024) hist[b] = 0;
    __syncthreads();
    int e0 = blockIdx.x * chunksz, e1 = min(E, e0 + chunksz);
    for (int e = e0 + tid; e < e1; e += 1024)
        atomicAdd(&hist[(unsigned)dst[e] / BSZ], 1);     // pass 1
    __syncthreads();
    int v = 0;
    if (tid < 512){ v = hist[tid]; ts[tid] = v; }
    __syncthreads();
    for (int s = 1; s < 512; s <<= 1){                   // scan local hist
        int tmp = (tid >= s && tid < 512) ? ts[tid - s] : 0;
        __syncthreads();
        if (tid < 512) ts[tid] += tmp;
        __syncthreads();
    }
    if (tid < 512){
        int excl = ts[tid] - v;
        lsb[tid] = excl;
        cur[tid] = excl;
        int padded = (v + 15) & ~15;                     // 64B multiple
        gbase[tid] = tid * CAP + (padded ? atomicAdd(&gcnt[tid], padded) : 0);
    }
    __syncthreads();
    for (int e = e0 + tid; e < e1; e += 1024){           // pass 2: scatter into LDS
        int d = dst[e];
        int buk = (unsigned)d / BSZ;
        int pos = atomicAdd(&cur[buk], 1);
        lstg[pos] = (unsigned)src[e] | ((unsigned)(d - buk * BSZ) << 17);
    }
    __syncthreads();
    // flush: wave w owns buckets w, w+16, ... — contiguous full-line bursts
    int wv = tid >> 6, ln = tid & 63;
    for (int b = wv; b < nbuk; b += 16){
        int cnt = hist[b];
        int padded = (cnt + 15) & ~15;
        int lb = lsb[b], gb = gbase[b];
        for (int j = ln; j < padded; j += 64)
            staged[gb + j] = (j < cnt) ? lstg[lb + j] : 0xFFFFFFFFu;
    }
}

// ---- per-bucket local sort (1024 threads): skip sentinels, per-dst (start,end), csr ----
__global__ void k_local(const unsigned* __restrict__ staged, const int* __restrict__ gcnt,
                        int2* __restrict__ offp, int* __restrict__ csr, int N){
    __shared__ int deg[BSZ];
    __shared__ int cur[BSZ];
    __shared__ int ts[256];
    int b = blockIdx.x, t = threadIdx.x;
    int lo = b * BSZ, hi = min(N, lo + BSZ);
    int e0 = b * CAP, e1 = e0 + gcnt[b];
    if (t < BSZ) deg[t] = 0;
    __syncthreads();
    for (int e = e0 + t; e < e1; e += 1024){
        unsigned se = staged[e];
        if (se != 0xFFFFFFFFu) atomicAdd(&deg[se >> 17], 1);
    }
    __syncthreads();
    int v = 0;
    if (t < 256){
        v = (t < BSZ) ? deg[t] : 0;
        ts[t] = v;
    }
    __syncthreads();
    for (int s = 1; s < 256; s <<= 1){            // 256-lane Hillis-Steele; others barrier-only
        int tmp = (t >= s && t < 256) ? ts[t - s] : 0;
        __syncthreads();
        if (t < 256) ts[t] += tmp;
        __syncthreads();
    }
    if (t < BSZ){
        cur[t] = e0 + ts[t] - v;
        if (lo + t < hi) offp[lo + t] = make_int2(e0 + ts[t] - v, e0 + ts[t]);
    }
    __syncthreads();
    for (int e = e0 + t; e < e1; e += 1024){
        unsigned se = staged[e];
        if (se == 0xFFFFFFFFu) continue;
        int pos = atomicAdd(&cur[se >> 17], 1);
        csr[pos] = (int)(se & 0x1FFFFu);
    }
}

// ---- layer 1 gather: 4-deep batch + fold-reduce + distributed epilogue ----
// wave per dst; lane = (edge slot g=lane>>3, chan oct q=lane&7), head h=q>>1.
__global__ void k_l1_gather(const int2* __restrict__ offp, const int* __restrict__ csr,
                            const uint2* __restrict__ asvb, const float* __restrict__ adv,
                            const unsigned char* __restrict__ xw1, const float* __restrict__ b1,
                            unsigned char* __restrict__ h1f8, int N){
    int tid = threadIdx.x;
    int wid = (int)(((long)blockIdx.x * 256 + tid) >> 6);
    if (wid >= N) return;
    int lane = tid & 63;
    int g = lane >> 3;          // edge slot 0..7
    int q = lane & 7;           // channel oct: channels q*8 .. q*8+7
    int h = q >> 1;             // head
    float advd = adv[wid * 4 + h];
    const unsigned char* xwq = xw1 + q * 8;                 // per-lane row base
    const char* asvbh = (const char*)asvb + h * 2;          // per-lane bf16 slot

    v2f acc2[4] = {{0.f, 0.f}, {0.f, 0.f}, {0.f, 0.f}, {0.f, 0.f}};
    float den = 0.f;
    int2 rng = offp[wid];
    int k = rng.x, end = rng.y;
    for (; k + 32 <= end; k += 32){         // 4 batches of 8 edges: all loads in flight
        int s0 = csr[k + g];
        int s1 = csr[k + 8 + g];
        int s2 = csr[k + 16 + g];
        int s3 = csr[k + 24 + g];
        uint2 r0 = *(const uint2*)(xwq + ((size_t)s0 << 6));
        uint2 r1 = *(const uint2*)(xwq + ((size_t)s1 << 6));
        uint2 r2 = *(const uint2*)(xwq + ((size_t)s2 << 6));
        uint2 r3 = *(const uint2*)(xwq + ((size_t)s3 << 6));
        float a0 = b2f(*(const unsigned short*)(asvbh + ((size_t)s0 << 3)));
        float a1 = b2f(*(const unsigned short*)(asvbh + ((size_t)s1 << 3)));
        float a2 = b2f(*(const unsigned short*)(asvbh + ((size_t)s2 << 3)));
        float a3 = b2f(*(const unsigned short*)(asvbh + ((size_t)s3 << 3)));
        float t0 = a0 + advd, t1 = a1 + advd, t2 = a2 + advd, t3 = a3 + advd;
        float w0 = __expf(fmaxf(t0, NEG * t0));
        float w1 = __expf(fmaxf(t1, NEG * t1));
        float w2 = __expf(fmaxf(t2, NEG * t2));
        float w3 = __expf(fmaxf(t3, NEG * t3));
        den += (w0 + w1) + (w2 + w3);
        fma8(r0, w0, acc2);
        fma8(r1, w1, acc2);
        fma8(r2, w2, acc2);
        fma8(r3, w3, acc2);
    }
    if (k + 16 <= end){                     // 2-batch step
        int sA = csr[k + g];
        int sB = csr[k + 8 + g];
        uint2 rA = *(const uint2*)(xwq + ((size_t)sA << 6));
        uint2 rB = *(const uint2*)(xwq + ((size_t)sB << 6));
        float aA = b2f(*(const unsigned short*)(asvbh + ((size_t)sA << 3)));
        float aB = b2f(*(const unsigned short*)(asvbh + ((size_t)sB << 3)));
        float tA = aA + advd, tB = aB + advd;
        float wA = __expf(fmaxf(tA, NEG * tA));
        float wB = __expf(fmaxf(tB, NEG * tB));
        den += wA + wB;
        fma8(rA, wA, acc2);
        fma8(rB, wB, acc2);
        k += 16;
    }
    for (; k < end; k += 8){                // masked tail
        int e = k + g;
        bool valid = e < end;
        int s = csr[valid ? e : end - 1];
        uint2 r = *(const uint2*)(xwq + ((size_t)s << 6));
        float a = b2f(*(const unsigned short*)(asvbh + ((size_t)s << 3)));
        float t = a + advd;
        float w = valid ? __expf(fmaxf(t, NEG * t)) : 0.f;
        den += w;
        fma8(r, w, acc2);
    }

    // ---- fold-reduce across the 8 edge slots (lane bits 3..5), keep-half per stage ----
    v2f t0, t1, t2, t3;
    t0.x = __shfl_xor(acc2[0].x, 32); t0.y = __shfl_xor(acc2[0].y, 32);
    t1.x = __shfl_xor(acc2[1].x, 32); t1.y = __shfl_xor(acc2[1].y, 32);
    t2.x = __shfl_xor(acc2[2].x, 32); t2.y = __shfl_xor(acc2[2].y, 32);
    t3.x = __shfl_xor(acc2[3].x, 32); t3.y = __shfl_xor(acc2[3].y, 32);
    bool gb2 = (lane & 32) != 0;                 // g bit2
    v2f n0 = gb2 ? (acc2[2] + t2) : (acc2[0] + t0);   // keep half holding my channel pair
    v2f n1 = gb2 ? (acc2[3] + t3) : (acc2[1] + t1);
    v2f u0, u1;
    u0.x = __shfl_xor(n0.x, 16); u0.y = __shfl_xor(n0.y, 16);
    u1.x = __shfl_xor(n1.x, 16); u1.y = __shfl_xor(n1.y, 16);
    bool gb1 = (lane & 16) != 0;                 // g bit1
    v2f rr = gb1 ? (n1 + u1) : (n0 + u0);
    v2f z;
    z.x = __shfl_xor(rr.x, 8); z.y = __shfl_xor(rr.y, 8);
    rr += z;                                     // summed over all 8 slots
    bool gb0 = (lane & 8) != 0;                  // g bit0 -> component
    den += __shfl_xor(den, 8);
    den += __shfl_xor(den, 16);
    den += __shfl_xor(den, 32);
    float val = gb0 ? rr.y : rr.x;               // total for channel c = q*8+g

    // ---- distributed epilogue: all 64 lanes; lane (g,q) owns channel c=q*8+g ----
    int c = q * 8 + g;
    float aself = b2f(*(const unsigned short*)(asvbh + ((size_t)wid << 3)));
    float tsv = aself + advd;
    float ws = __expf(fmaxf(tsv, NEG * tsv));               // self-loop weight (per head)
    unsigned selfb = xw1[(size_t)wid * 64 + c];             // coalesced byte load
    v2f sf = __builtin_amdgcn_cvt_pk_f32_fp8(selfb, false); // sf.x = fp8(byte0)
    float asel = val + ws * sf.x;
    float inv = 1.0f / (den + ws + 1e-16f);
    float o = elufast(asel * inv + b1[c]);
    unsigned p = __builtin_amdgcn_cvt_pk_fp8_f32(o, o, 0, false);
    h1f8[(size_t)wid * 64 + c] = (unsigned char)p;          // coalesced byte store
}

// ---- layer 2 node transform (packed v2f + b64 LDS reads): xw2[N,8], adv2[N,4] ----
__global__ void k_l2_node(const unsigned char* __restrict__ h1f8, const float* __restrict__ W2,
                          const float* __restrict__ ad2, float* __restrict__ xw2,
                          float* __restrict__ adv2, int N){
    __shared__ float sW[512], sD[8];
    int tid = threadIdx.x;
    sW[tid] = W2[tid];
    sW[256 + tid] = W2[256 + tid];
    if (tid < 8) sD[tid] = ad2[tid];
    __syncthreads();
    int i = blockIdx.x * 256 + tid;
    if (i >= N) return;
    const uint2* rp = (const uint2*)(h1f8 + (size_t)i * 64);
    v2f acc2[4] = {{0.f, 0.f}, {0.f, 0.f}, {0.f, 0.f}, {0.f, 0.f}};
    #pragma unroll
    for (int b8 = 0; b8 < 8; b8++){
        uint2 r = rp[b8];
        v2f f0 = __builtin_amdgcn_cvt_pk_f32_fp8(r.x, false);
        v2f f1 = __builtin_amdgcn_cvt_pk_f32_fp8(r.x, true);
        v2f f2 = __builtin_amdgcn_cvt_pk_f32_fp8(r.y, false);
        v2f f3 = __builtin_amdgcn_cvt_pk_f32_fp8(r.y, true);
        float f[8] = {f0.x, f0.y, f1.x, f1.y, f2.x, f2.y, f3.x, f3.y};
        #pragma unroll
        for (int j = 0; j < 8; j++){
            v2f hcv = {f[j], f[j]};
            const v2f* wrow = (const v2f*)&sW[(b8 * 8 + j) * 8];   // broadcast b64 reads
            acc2[0] = __builtin_elementwise_fma(hcv, wrow[0], acc2[0]);
            acc2[1] = __builtin_elementwise_fma(hcv, wrow[1], acc2[1]);
            acc2[2] = __builtin_elementwise_fma(hcv, wrow[2], acc2[2]);
            acc2[3] = __builtin_elementwise_fma(hcv, wrow[3], acc2[3]);
        }
    }
    float4* xo = (float4*)(xw2 + (size_t)i * 8);
    xo[0] = make_float4(acc2[0].x, acc2[0].y, acc2[1].x, acc2[1].y);
    xo[1] = make_float4(acc2[2].x, acc2[2].y, acc2[3].x, acc2[3].y);
    float4 dv;
    dv.x = acc2[0].x * sD[0] + acc2[0].y * sD[1];
    dv.y = acc2[1].x * sD[2] + acc2[1].y * sD[3];
    dv.z = acc2[2].x * sD[4] + acc2[2].y * sD[5];
    dv.w = acc2[3].x * sD[6] + acc2[3].y * sD[7];
    *(float4*)(adv2 + (size_t)i * 4) = dv;
}

// ---- layer 2 gather: lane = (edge slot g=lane>>2 0..15, head hh=lane&3) ----
__global__ void k_l2_gather(const int2* __restrict__ offp, const int* __restrict__ csr,
                            const float* __restrict__ adv2, const float* __restrict__ xw2,
                            const float* __restrict__ b2, const float* __restrict__ as2,
                            float* __restrict__ pool, int N){
    __shared__ float lpool[8];
    int tid = threadIdx.x;
    if (tid < 8) lpool[tid] = 0.f;
    __syncthreads();
    int wid = (int)(((long)blockIdx.x * 256 + tid) >> 6);
    if (wid < N){
        int lane = tid & 63;
        int g = lane >> 2;          // edge slot 0..15
        int hh = lane & 3;          // head
        float2 a2h = *(const float2*)&as2[hh * 2];
        float advd = adv2[wid * 4 + hh];
        const char* xwh = (const char*)xw2 + hh * 8;
        v2f accv = {0.f, 0.f};
        float den = 0.f;

        auto edge = [&](int s, bool valid){
            v2f v = *(const v2f*)(xwh + ((size_t)s << 5));
            float al = v.x * a2h.x + v.y * a2h.y;
            float t = al + advd;
            float w = valid ? __expf(fmaxf(t, NEG * t)) : 0.f;
            den += w;
            v2f w2 = {w, w};
            accv = __builtin_elementwise_fma(v, w2, accv);
        };

        int2 rng = offp[wid];
        int k = rng.x, end = rng.y;
        for (; k + 32 <= end; k += 32){     // 2 batches of 16 edges in flight
            int s0 = csr[k + g], s1 = csr[k + 16 + g];
            edge(s0, true); edge(s1, true);
        }
        for (; k < end; k += 16){           // masked tail
            int e = k + g;
            bool valid = e < end;
            int s = csr[valid ? e : end - 1];
            edge(s, valid);
        }
        // reduce over edge slots (lane bits 2..5)
        #pragma unroll
        for (int m = 4; m <= 32; m <<= 1){
            accv.x += __shfl_xor(accv.x, m);
            accv.y += __shfl_xor(accv.y, m);
            den    += __shfl_xor(den, m);
        }
        if (g == 0){                         // lanes 0..3, lane hh owns head hh
            v2f v = *(const v2f*)(xwh + ((size_t)wid << 5));
            float al = v.x * a2h.x + v.y * a2h.y;
            float t = al + advd;
            float ws = __expf(fmaxf(t, NEG * t));
            den += ws;
            accv.x += ws * v.x;
            accv.y += ws * v.y;
            float inv = 1.0f / (den + 1e-16f);
            float o0 = elufast(accv.x * inv + b2[hh * 2]);
            float o1 = elufast(accv.y * inv + b2[hh * 2 + 1]);
            atomicAdd(&lpool[hh * 2], o0);
            atomicAdd(&lpool[hh * 2 + 1], o1);
        }
    }
    __syncthreads();
    if (tid < 8) atomicAdd(&pool[(blockIdx.x & 63) * 8 + tid], lpool[tid]);
}

// ---- output head: reduce 64x8 pool partials, apply mean+W+sigmoid ----
__global__ void k_final(const float* __restrict__ pool, const float* __restrict__ Wout,
                        const float* __restrict__ bout, float* __restrict__ out, float invN){
    int lane = threadIdx.x;      // 64 lanes, lane l owns slot l
    const float4* p4 = (const float4*)(pool + lane * 8);
    float4 a = p4[0], b = p4[1];
    float v[8] = {a.x, a.y, a.z, a.w, b.x, b.y, b.z, b.w};
    #pragma unroll
    for (int m = 1; m <= 32; m <<= 1){
        #pragma unroll
        for (int j = 0; j < 8; j++) v[j] += __shfl_xor(v[j], m);
    }
    if (lane == 0){
        float z = bout[0];
        #pragma unroll
        for (int j = 0; j < 8; j++) z += v[j] * invN * Wout[j];
        out[0] = 1.0f / (1.0f + __expf(-z));
    }
}

extern "C" void kernel_launch(void* const* d_in, const int* in_sizes, int n_in,
                              void* d_out, int out_size, void* d_ws, size_t ws_size,
                              hipStream_t stream){
    const float* x    = (const float*)d_in[0];
    const int*   ei   = (const int*)d_in[1];     // int32
    const float* W1   = (const float*)d_in[2];
    const float* as1  = (const float*)d_in[3];
    const float* ad1  = (const float*)d_in[4];
    const float* b1   = (const float*)d_in[5];
    const float* W2   = (const float*)d_in[6];
    const float* as2  = (const float*)d_in[7];
    const float* ad2  = (const float*)d_in[8];
    const float* b2   = (const float*)d_in[9];
    const float* Wout = (const float*)d_in[10];
    const float* bout = (const float*)d_in[11];
    float* out = (float*)d_out;

    int N = in_sizes[0] / 4;
    int E = in_sizes[1] / 2;
    const int* src = ei;
    const int* dst = ei + E;

    char* ws = (char*)d_ws;
    size_t off_b = 0;
    auto alloc = [&](size_t bytes)->void*{
        void* p = ws + off_b;
        off_b += (bytes + 255) & ~(size_t)255;
        return p;
    };
    unsigned char* xw1  = (unsigned char*)alloc((size_t)N * 64);  // fp8 e4m3
    unsigned char* h1f8 = (unsigned char*)alloc((size_t)N * 64);  // fp8 e4m3 h1
    uint2*    asvb   = (uint2*)alloc((size_t)N * 8);              // bf16x4 alpha_src
    float*    adv    = (float*)alloc((size_t)N * 4 * 4);
    float*    adv2   = (float*)alloc((size_t)N * 4 * 4);
    int*      gcnt   = (int*)alloc((size_t)MAXBUK * 4);           // per-bucket fill count
    unsigned* staged = (unsigned*)alloc((size_t)MAXBUK * CAP * 4);// slab: src | localdst<<17
    int2*     offp   = (int2*)alloc((size_t)N * 8);               // per-dst (start,end)
    int*      csr    = (int*)alloc((size_t)MAXBUK * CAP * 4);     // slab csr
    float*    xw2    = (float*)alloc((size_t)N * 8 * 4);
    float*    pool   = (float*)alloc(64 * 8 * 4);

    int nbuk = (N + BSZ - 1) / BSZ;          // 447
    int chunksz = (E + NBIN - 1) / NBIN;     // 6250 <= LSTG

    hipMemsetAsync(pool, 0, 64 * 8 * 4, stream);
    hipMemsetAsync(gcnt, 0, (size_t)MAXBUK * 4, stream);

    // slab binning (LDS-staged, full-line flush) + per-bucket local sort
    k_bin2<<<NBIN, 1024, 0, stream>>>(src, dst, gcnt, staged, E, chunksz, nbuk);
    k_l1_node<<<(N + 255) / 256, 256, 0, stream>>>(x, W1, as1, ad1, xw1, asvb, adv, N);
    k_local<<<nbuk, 1024, 0, stream>>>(staged, gcnt, offp, csr, N);

    // layer 1 gather (4-deep batch + fold-reduce + distributed epilogue -> h1 fp8)
    k_l1_gather<<<(int)(((long)N * 64 + 255) / 256), 256, 0, stream>>>(
        offp, csr, asvb, adv, xw1, b1, h1f8, N);
    // dense layer-2 node transform (packed)
    k_l2_node<<<(N + 255) / 256, 256, 0, stream>>>(h1f8, W2, ad2, xw2, adv2, N);
    // layer 2 gather + fused mean pool
    k_l2_gather<<<(int)(((long)N * 64 + 255) / 256), 256, 0, stream>>>(
        offp, csr, adv2, xw2, b2, as2, pool, N);
    // head
    k_final<<<1, 64, 0, stream>>>(pool, Wout, bout, out, 1.0f / (float)N);
}

// Round 12
// 161.584 us; speedup vs baseline: 1.0973x; 1.0423x over previous
//
#include <hip/hip_runtime.h>
#include <hip/hip_fp8.h>

#define NEG 0.2f
#define BSZ 224          // nodes per dst bucket
#define MAXBUK 512       // >= ceil(N/BSZ) = 447
#define NBIN 512         // binning blocks
#define CAP 16384        // slab capacity per bucket (max padded load ~10K at E=3.2M)
#define LSTG 6400        // LDS staging entries (>= chunksz = ceil(E/NBIN) = 6250)

typedef float v2f __attribute__((ext_vector_type(2)));

__device__ __forceinline__ float elufast(float x){ return x > 0.0f ? x : __expf(x) - 1.0f; }
__device__ __forceinline__ float b2f(unsigned short b){ return __uint_as_float((unsigned)b << 16); }
__device__ __forceinline__ unsigned short f2b(float x){
    unsigned u = __float_as_uint(x);
    return (unsigned short)((u + 0x7FFFu + ((u >> 16) & 1u)) >> 16);   // RNE
}

// decode 8 fp8-e4m3 (uint2) via HW v_cvt_pk_f32_fp8, accumulate with packed fma (v_pk_fma_f32)
__device__ __forceinline__ void fma8(uint2 r, float w, v2f* acc){
    v2f w2 = {w, w};
    v2f f0 = __builtin_amdgcn_cvt_pk_f32_fp8(r.x, false);
    v2f f1 = __builtin_amdgcn_cvt_pk_f32_fp8(r.x, true);
    v2f f2 = __builtin_amdgcn_cvt_pk_f32_fp8(r.y, false);
    v2f f3 = __builtin_amdgcn_cvt_pk_f32_fp8(r.y, true);
    acc[0] = __builtin_elementwise_fma(f0, w2, acc[0]);
    acc[1] = __builtin_elementwise_fma(f1, w2, acc[1]);
    acc[2] = __builtin_elementwise_fma(f2, w2, acc[2]);
    acc[3] = __builtin_elementwise_fma(f3, w2, acc[3]);
}

// ---- layer 1 node transform (packed v2f): xw1(fp8)[N,64], asvb(bf16x4)[N], adv[N,4] ----
__global__ void k_l1_node(const float* __restrict__ x, const float* __restrict__ W1,
                          const float* __restrict__ as1, const float* __restrict__ ad1,
                          unsigned char* __restrict__ xw1, uint2* __restrict__ asvb,
                          float* __restrict__ adv, int N){
    __shared__ float sW[256], sA[64], sD[64];
    int tid = threadIdx.x;
    sW[tid] = W1[tid];
    if (tid < 64){ sA[tid] = as1[tid]; sD[tid] = ad1[tid]; }
    __syncthreads();
    int i = blockIdx.x * 256 + tid;
    if (i >= N) return;
    float4 xv = ((const float4*)x)[i];
    const v2f* sW0 = (const v2f*)sW;
    const v2f* sW1v = (const v2f*)(sW + 64);
    const v2f* sW2v = (const v2f*)(sW + 128);
    const v2f* sW3v = (const v2f*)(sW + 192);
    v2f xx = {xv.x, xv.x}, yy = {xv.y, xv.y}, zz = {xv.z, xv.z}, ww = {xv.w, xv.w};
    v2f xwv[32];
    #pragma unroll
    for (int j = 0; j < 32; j++){
        v2f t = xx * sW0[j];
        t = __builtin_elementwise_fma(yy, sW1v[j], t);
        t = __builtin_elementwise_fma(zz, sW2v[j], t);
        t = __builtin_elementwise_fma(ww, sW3v[j], t);
        xwv[j] = t;
    }
    unsigned wv[16];
    #pragma unroll
    for (int j = 0; j < 16; j++){
        unsigned p = 0;
        p = __builtin_amdgcn_cvt_pk_fp8_f32(xwv[2 * j].x,     xwv[2 * j].y,     p, false);
        p = __builtin_amdgcn_cvt_pk_fp8_f32(xwv[2 * j + 1].x, xwv[2 * j + 1].y, p, true);
        wv[j] = p;
    }
    uint4* dp = (uint4*)(xw1 + (size_t)i * 64);
    dp[0] = make_uint4(wv[0],  wv[1],  wv[2],  wv[3]);
    dp[1] = make_uint4(wv[4],  wv[5],  wv[6],  wv[7]);
    dp[2] = make_uint4(wv[8],  wv[9],  wv[10], wv[11]);
    dp[3] = make_uint4(wv[12], wv[13], wv[14], wv[15]);
    const v2f* sAv = (const v2f*)sA;
    const v2f* sDv = (const v2f*)sD;
    float al[4];
    #pragma unroll
    for (int h = 0; h < 4; h++){
        v2f asv = {0.f, 0.f}, adw = {0.f, 0.f};
        #pragma unroll
        for (int c2 = 0; c2 < 8; c2++){
            asv = __builtin_elementwise_fma(xwv[h * 8 + c2], sAv[h * 8 + c2], asv);
            adw = __builtin_elementwise_fma(xwv[h * 8 + c2], sDv[h * 8 + c2], adw);
        }
        al[h] = asv.x + asv.y;
        adv[i * 4 + h] = adw.x + adw.y;
    }
    asvb[i] = make_uint2((unsigned)f2b(al[0]) | ((unsigned)f2b(al[1]) << 16),
                         (unsigned)f2b(al[2]) | ((unsigned)f2b(al[3]) << 16));
}

// ---- slab binning with LDS staging: int4-vectorized edge loops (4x MLP on atomic chains),
// scatter to LDS, flush full-line bursts. Slab b: [b*CAP, b*CAP+gcnt[b]); pad = sentinel ----
__global__ void k_bin2(const int* __restrict__ src, const int* __restrict__ dst,
                       int* __restrict__ gcnt, unsigned* __restrict__ staged,
                       int E, int chunksz, int nbuk){
    __shared__ int hist[MAXBUK];
    __shared__ int cur[MAXBUK];     // LDS insert cursor
    __shared__ int lsb[MAXBUK];     // local start in lstg
    __shared__ int gbase[MAXBUK];   // reserved global base (64B aligned)
    __shared__ int ts[512];
    __shared__ unsigned lstg[LSTG]; // block-local sorted edges (~25 KB)
    int tid = threadIdx.x;
    for (int b = tid; b < MAXBUK; b += 1024) hist[b] = 0;
    __syncthreads();
    int e0 = blockIdx.x * chunksz, e1 = min(E, e0 + chunksz);
    int a0 = min(e1, (e0 + 3) & ~3);         // aligned start
    int a1 = max(a0, e1 & ~3);               // aligned end
    // ---- pass 1: count (head / int4 body / tail) ----
    if (tid < a0 - e0) atomicAdd(&hist[(unsigned)dst[e0 + tid] / BSZ], 1);
    for (int q = (a0 >> 2) + tid; q < (a1 >> 2); q += 1024){
        int4 d4 = ((const int4*)dst)[q];
        atomicAdd(&hist[(unsigned)d4.x / BSZ], 1);
        atomicAdd(&hist[(unsigned)d4.y / BSZ], 1);
        atomicAdd(&hist[(unsigned)d4.z / BSZ], 1);
        atomicAdd(&hist[(unsigned)d4.w / BSZ], 1);
    }
    if (tid < e1 - a1) atomicAdd(&hist[(unsigned)dst[a1 + tid] / BSZ], 1);
    __syncthreads();
    int v = 0;
    if (tid < 512){ v = hist[tid]; ts[tid] = v; }
    __syncthreads();
    for (int s = 1; s < 512; s <<= 1){                   // scan local hist
        int tmp = (tid >= s && tid < 512) ? ts[tid - s] : 0;
        __syncthreads();
        if (tid < 512) ts[tid] += tmp;
        __syncthreads();
    }
    if (tid < 512){
        int excl = ts[tid] - v;
        lsb[tid] = excl;
        cur[tid] = excl;
        int padded = (v + 15) & ~15;                     // 64B multiple
        gbase[tid] = tid * CAP + (padded ? atomicAdd(&gcnt[tid], padded) : 0);
    }
    __syncthreads();
    // ---- pass 2: scatter into LDS (head / int4 body / tail) ----
    auto put = [&](int d, int s){
        int buk = (unsigned)d / BSZ;
        int pos = atomicAdd(&cur[buk], 1);
        lstg[pos] = (unsigned)s | ((unsigned)(d - buk * BSZ) << 17);
    };
    if (tid < a0 - e0) put(dst[e0 + tid], src[e0 + tid]);
    for (int q = (a0 >> 2) + tid; q < (a1 >> 2); q += 1024){
        int4 d4 = ((const int4*)dst)[q];
        int4 s4 = ((const int4*)src)[q];
        put(d4.x, s4.x); put(d4.y, s4.y); put(d4.z, s4.z); put(d4.w, s4.w);
    }
    if (tid < e1 - a1) put(dst[a1 + tid], src[a1 + tid]);
    __syncthreads();
    // ---- flush: wave w owns buckets w, w+16, ... — contiguous full-line bursts ----
    int wv = tid >> 6, ln = tid & 63;
    for (int b = wv; b < nbuk; b += 16){
        int cnt = hist[b];
        int padded = (cnt + 15) & ~15;
        int lb = lsb[b], gb = gbase[b];
        for (int j = ln; j < padded; j += 64)
            staged[gb + j] = (j < cnt) ? lstg[lb + j] : 0xFFFFFFFFu;
    }
}

// ---- per-bucket local sort: uint4-vectorized passes (slab ranges 16-entry aligned) ----
__global__ void k_local(const unsigned* __restrict__ staged, const int* __restrict__ gcnt,
                        int2* __restrict__ offp, int* __restrict__ csr, int N){
    __shared__ int deg[BSZ];
    __shared__ int cur[BSZ];
    __shared__ int ts[256];
    int b = blockIdx.x, t = threadIdx.x;
    int lo = b * BSZ, hi = min(N, lo + BSZ);
    int e0 = b * CAP, e1 = e0 + gcnt[b];     // both multiples of 16
    if (t < BSZ) deg[t] = 0;
    __syncthreads();
    for (int q = (e0 >> 2) + t; q < (e1 >> 2); q += 1024){
        uint4 s4 = ((const uint4*)staged)[q];
        if (s4.x != 0xFFFFFFFFu) atomicAdd(&deg[s4.x >> 17], 1);
        if (s4.y != 0xFFFFFFFFu) atomicAdd(&deg[s4.y >> 17], 1);
        if (s4.z != 0xFFFFFFFFu) atomicAdd(&deg[s4.z >> 17], 1);
        if (s4.w != 0xFFFFFFFFu) atomicAdd(&deg[s4.w >> 17], 1);
    }
    __syncthreads();
    int v = 0;
    if (t < 256){
        v = (t < BSZ) ? deg[t] : 0;
        ts[t] = v;
    }
    __syncthreads();
    for (int s = 1; s < 256; s <<= 1){            // 256-lane Hillis-Steele; others barrier-only
        int tmp = (t >= s && t < 256) ? ts[t - s] : 0;
        __syncthreads();
        if (t < 256) ts[t] += tmp;
        __syncthreads();
    }
    if (t < BSZ){
        cur[t] = e0 + ts[t] - v;
        if (lo + t < hi) offp[lo + t] = make_int2(e0 + ts[t] - v, e0 + ts[t]);
    }
    __syncthreads();
    auto sc = [&](unsigned se){
        if (se == 0xFFFFFFFFu) return;
        int pos = atomicAdd(&cur[se >> 17], 1);
        csr[pos] = (int)(se & 0x1FFFFu);
    };
    for (int q = (e0 >> 2) + t; q < (e1 >> 2); q += 1024){
        uint4 s4 = ((const uint4*)staged)[q];
        sc(s4.x); sc(s4.y); sc(s4.z); sc(s4.w);
    }
}

// ---- layer 1 gather: 4-deep batch + fold-reduce + distributed epilogue ----
// wave per dst; lane = (edge slot g=lane>>3, chan oct q=lane&7), head h=q>>1.
__global__ void k_l1_gather(const int2* __restrict__ offp, const int* __restrict__ csr,
                            const uint2* __restrict__ asvb, const float* __restrict__ adv,
                            const unsigned char* __restrict__ xw1, const float* __restrict__ b1,
                            unsigned char* __restrict__ h1f8, int N){
    int tid = threadIdx.x;
    int wid = (int)(((long)blockIdx.x * 256 + tid) >> 6);
    if (wid >= N) return;
    int lane = tid & 63;
    int g = lane >> 3;          // edge slot 0..7
    int q = lane & 7;           // channel oct: channels q*8 .. q*8+7
    int h = q >> 1;             // head
    float advd = adv[wid * 4 + h];
    const unsigned char* xwq = xw1 + q * 8;                 // per-lane row base
    const char* asvbh = (const char*)asvb + h * 2;          // per-lane bf16 slot

    v2f acc2[4] = {{0.f, 0.f}, {0.f, 0.f}, {0.f, 0.f}, {0.f, 0.f}};
    float den = 0.f;
    int2 rng = offp[wid];
    int k = rng.x, end = rng.y;
    for (; k + 32 <= end; k += 32){         // 4 batches of 8 edges: all loads in flight
        int s0 = csr[k + g];
        int s1 = csr[k + 8 + g];
        int s2 = csr[k + 16 + g];
        int s3 = csr[k + 24 + g];
        uint2 r0 = *(const uint2*)(xwq + ((size_t)s0 << 6));
        uint2 r1 = *(const uint2*)(xwq + ((size_t)s1 << 6));
        uint2 r2 = *(const uint2*)(xwq + ((size_t)s2 << 6));
        uint2 r3 = *(const uint2*)(xwq + ((size_t)s3 << 6));
        float a0 = b2f(*(const unsigned short*)(asvbh + ((size_t)s0 << 3)));
        float a1 = b2f(*(const unsigned short*)(asvbh + ((size_t)s1 << 3)));
        float a2 = b2f(*(const unsigned short*)(asvbh + ((size_t)s2 << 3)));
        float a3 = b2f(*(const unsigned short*)(asvbh + ((size_t)s3 << 3)));
        float t0 = a0 + advd, t1 = a1 + advd, t2 = a2 + advd, t3 = a3 + advd;
        float w0 = __expf(fmaxf(t0, NEG * t0));
        float w1 = __expf(fmaxf(t1, NEG * t1));
        float w2 = __expf(fmaxf(t2, NEG * t2));
        float w3 = __expf(fmaxf(t3, NEG * t3));
        den += (w0 + w1) + (w2 + w3);
        fma8(r0, w0, acc2);
        fma8(r1, w1, acc2);
        fma8(r2, w2, acc2);
        fma8(r3, w3, acc2);
    }
    if (k + 16 <= end){                     // 2-batch step
        int sA = csr[k + g];
        int sB = csr[k + 8 + g];
        uint2 rA = *(const uint2*)(xwq + ((size_t)sA << 6));
        uint2 rB = *(const uint2*)(xwq + ((size_t)sB << 6));
        float aA = b2f(*(const unsigned short*)(asvbh + ((size_t)sA << 3)));
        float aB = b2f(*(const unsigned short*)(asvbh + ((size_t)sB << 3)));
        float tA = aA + advd, tB = aB + advd;
        float wA = __expf(fmaxf(tA, NEG * tA));
        float wB = __expf(fmaxf(tB, NEG * tB));
        den += wA + wB;
        fma8(rA, wA, acc2);
        fma8(rB, wB, acc2);
        k += 16;
    }
    for (; k < end; k += 8){                // masked tail
        int e = k + g;
        bool valid = e < end;
        int s = csr[valid ? e : end - 1];
        uint2 r = *(const uint2*)(xwq + ((size_t)s << 6));
        float a = b2f(*(const unsigned short*)(asvbh + ((size_t)s << 3)));
        float t = a + advd;
        float w = valid ? __expf(fmaxf(t, NEG * t)) : 0.f;
        den += w;
        fma8(r, w, acc2);
    }

    // ---- fold-reduce across the 8 edge slots (lane bits 3..5), keep-half per stage ----
    v2f t0, t1, t2, t3;
    t0.x = __shfl_xor(acc2[0].x, 32); t0.y = __shfl_xor(acc2[0].y, 32);
    t1.x = __shfl_xor(acc2[1].x, 32); t1.y = __shfl_xor(acc2[1].y, 32);
    t2.x = __shfl_xor(acc2[2].x, 32); t2.y = __shfl_xor(acc2[2].y, 32);
    t3.x = __shfl_xor(acc2[3].x, 32); t3.y = __shfl_xor(acc2[3].y, 32);
    bool gb2 = (lane & 32) != 0;                 // g bit2
    v2f n0 = gb2 ? (acc2[2] + t2) : (acc2[0] + t0);   // keep half holding my channel pair
    v2f n1 = gb2 ? (acc2[3] + t3) : (acc2[1] + t1);
    v2f u0, u1;
    u0.x = __shfl_xor(n0.x, 16); u0.y = __shfl_xor(n0.y, 16);
    u1.x = __shfl_xor(n1.x, 16); u1.y = __shfl_xor(n1.y, 16);
    bool gb1 = (lane & 16) != 0;                 // g bit1
    v2f rr = gb1 ? (n1 + u1) : (n0 + u0);
    v2f z;
    z.x = __shfl_xor(rr.x, 8); z.y = __shfl_xor(rr.y, 8);
    rr += z;                                     // summed over all 8 slots
    bool gb0 = (lane & 8) != 0;                  // g bit0 -> component
    den += __shfl_xor(den, 8);
    den += __shfl_xor(den, 16);
    den += __shfl_xor(den, 32);
    float val = gb0 ? rr.y : rr.x;               // total for channel c = q*8+g

    // ---- distributed epilogue: all 64 lanes; lane (g,q) owns channel c=q*8+g ----
    int c = q * 8 + g;
    float aself = b2f(*(const unsigned short*)(asvbh + ((size_t)wid << 3)));
    float tsv = aself + advd;
    float ws = __expf(fmaxf(tsv, NEG * tsv));               // self-loop weight (per head)
    unsigned selfb = xw1[(size_t)wid * 64 + c];             // coalesced byte load
    v2f sf = __builtin_amdgcn_cvt_pk_f32_fp8(selfb, false); // sf.x = fp8(byte0)
    float asel = val + ws * sf.x;
    float inv = 1.0f / (den + ws + 1e-16f);
    float o = elufast(asel * inv + b1[c]);
    unsigned p = __builtin_amdgcn_cvt_pk_fp8_f32(o, o, 0, false);
    h1f8[(size_t)wid * 64 + c] = (unsigned char)p;          // coalesced byte store
}

// ---- layer 2 node transform (packed v2f + b64 LDS reads): xw2[N,8], adv2[N,4] ----
__global__ void k_l2_node(const unsigned char* __restrict__ h1f8, const float* __restrict__ W2,
                          const float* __restrict__ ad2, float* __restrict__ xw2,
                          float* __restrict__ adv2, int N){
    __shared__ float sW[512], sD[8];
    int tid = threadIdx.x;
    sW[tid] = W2[tid];
    sW[256 + tid] = W2[256 + tid];
    if (tid < 8) sD[tid] = ad2[tid];
    __syncthreads();
    int i = blockIdx.x * 256 + tid;
    if (i >= N) return;
    const uint2* rp = (const uint2*)(h1f8 + (size_t)i * 64);
    v2f acc2[4] = {{0.f, 0.f}, {0.f, 0.f}, {0.f, 0.f}, {0.f, 0.f}};
    #pragma unroll
    for (int b8 = 0; b8 < 8; b8++){
        uint2 r = rp[b8];
        v2f f0 = __builtin_amdgcn_cvt_pk_f32_fp8(r.x, false);
        v2f f1 = __builtin_amdgcn_cvt_pk_f32_fp8(r.x, true);
        v2f f2 = __builtin_amdgcn_cvt_pk_f32_fp8(r.y, false);
        v2f f3 = __builtin_amdgcn_cvt_pk_f32_fp8(r.y, true);
        float f[8] = {f0.x, f0.y, f1.x, f1.y, f2.x, f2.y, f3.x, f3.y};
        #pragma unroll
        for (int j = 0; j < 8; j++){
            v2f hcv = {f[j], f[j]};
            const v2f* wrow = (const v2f*)&sW[(b8 * 8 + j) * 8];   // broadcast b64 reads
            acc2[0] = __builtin_elementwise_fma(hcv, wrow[0], acc2[0]);
            acc2[1] = __builtin_elementwise_fma(hcv, wrow[1], acc2[1]);
            acc2[2] = __builtin_elementwise_fma(hcv, wrow[2], acc2[2]);
            acc2[3] = __builtin_elementwise_fma(hcv, wrow[3], acc2[3]);
        }
    }
    float4* xo = (float4*)(xw2 + (size_t)i * 8);
    xo[0] = make_float4(acc2[0].x, acc2[0].y, acc2[1].x, acc2[1].y);
    xo[1] = make_float4(acc2[2].x, acc2[2].y, acc2[3].x, acc2[3].y);
    float4 dv;
    dv.x = acc2[0].x * sD[0] + acc2[0].y * sD[1];
    dv.y = acc2[1].x * sD[2] + acc2[1].y * sD[3];
    dv.z = acc2[2].x * sD[4] + acc2[2].y * sD[5];
    dv.w = acc2[3].x * sD[6] + acc2[3].y * sD[7];
    *(float4*)(adv2 + (size_t)i * 4) = dv;
}

// ---- layer 2 gather: lane = (edge slot g=lane>>2 0..15, head hh=lane&3) ----
__global__ void k_l2_gather(const int2* __restrict__ offp, const int* __restrict__ csr,
                            const float* __restrict__ adv2, const float* __restrict__ xw2,
                            const float* __restrict__ b2, const float* __restrict__ as2,
                            float* __restrict__ pool, int N){
    __shared__ float lpool[8];
    int tid = threadIdx.x;
    if (tid < 8) lpool[tid] = 0.f;
    __syncthreads();
    int wid = (int)(((long)blockIdx.x * 256 + tid) >> 6);
    if (wid < N){
        int lane = tid & 63;
        int g = lane >> 2;          // edge slot 0..15
        int hh = lane & 3;          // head
        float2 a2h = *(const float2*)&as2[hh * 2];
        float advd = adv2[wid * 4 + hh];
        const char* xwh = (const char*)xw2 + hh * 8;
        v2f accv = {0.f, 0.f};
        float den = 0.f;

        auto edge = [&](int s, bool valid){
            v2f v = *(const v2f*)(xwh + ((size_t)s << 5));
            float al = v.x * a2h.x + v.y * a2h.y;
            float t = al + advd;
            float w = valid ? __expf(fmaxf(t, NEG * t)) : 0.f;
            den += w;
            v2f w2 = {w, w};
            accv = __builtin_elementwise_fma(v, w2, accv);
        };

        int2 rng = offp[wid];
        int k = rng.x, end = rng.y;
        for (; k + 32 <= end; k += 32){     // 2 batches of 16 edges in flight
            int s0 = csr[k + g], s1 = csr[k + 16 + g];
            edge(s0, true); edge(s1, true);
        }
        for (; k < end; k += 16){           // masked tail
            int e = k + g;
            bool valid = e < end;
            int s = csr[valid ? e : end - 1];
            edge(s, valid);
        }
        // reduce over edge slots (lane bits 2..5)
        #pragma unroll
        for (int m = 4; m <= 32; m <<= 1){
            accv.x += __shfl_xor(accv.x, m);
            accv.y += __shfl_xor(accv.y, m);
            den    += __shfl_xor(den, m);
        }
        if (g == 0){                         // lanes 0..3, lane hh owns head hh
            v2f v = *(const v2f*)(xwh + ((size_t)wid << 5));
            float al = v.x * a2h.x + v.y * a2h.y;
            float t = al + advd;
            float ws = __expf(fmaxf(t, NEG * t));
            den += ws;
            accv.x += ws * v.x;
            accv.y += ws * v.y;
            float inv = 1.0f / (den + 1e-16f);
            float o0 = elufast(accv.x * inv + b2[hh * 2]);
            float o1 = elufast(accv.y * inv + b2[hh * 2 + 1]);
            atomicAdd(&lpool[hh * 2], o0);
            atomicAdd(&lpool[hh * 2 + 1], o1);
        }
    }
    __syncthreads();
    if (tid < 8) atomicAdd(&pool[(blockIdx.x & 63) * 8 + tid], lpool[tid]);
}

// ---- output head: reduce 64x8 pool partials, apply mean+W+sigmoid ----
__global__ void k_final(const float* __restrict__ pool, const float* __restrict__ Wout,
                        const float* __restrict__ bout, float* __restrict__ out, float invN){
    int lane = threadIdx.x;      // 64 lanes, lane l owns slot l
    const float4* p4 = (const float4*)(pool + lane * 8);
    float4 a = p4[0], b = p4[1];
    float v[8] = {a.x, a.y, a.z, a.w, b.x, b.y, b.z, b.w};
    #pragma unroll
    for (int m = 1; m <= 32; m <<= 1){
        #pragma unroll
        for (int j = 0; j < 8; j++) v[j] += __shfl_xor(v[j], m);
    }
    if (lane == 0){
        float z = bout[0];
        #pragma unroll
        for (int j = 0; j < 8; j++) z += v[j] * invN * Wout[j];
        out[0] = 1.0f / (1.0f + __expf(-z));
    }
}

extern "C" void kernel_launch(void* const* d_in, const int* in_sizes, int n_in,
                              void* d_out, int out_size, void* d_ws, size_t ws_size,
                              hipStream_t stream){
    const float* x    = (const float*)d_in[0];
    const int*   ei   = (const int*)d_in[1];     // int32
    const float* W1   = (const float*)d_in[2];
    const float* as1  = (const float*)d_in[3];
    const float* ad1  = (const float*)d_in[4];
    const float* b1   = (const float*)d_in[5];
    const float* W2   = (const float*)d_in[6];
    const float* as2  = (const float*)d_in[7];
    const float* ad2  = (const float*)d_in[8];
    const float* b2   = (const float*)d_in[9];
    const float* Wout = (const float*)d_in[10];
    const float* bout = (const float*)d_in[11];
    float* out = (float*)d_out;

    int N = in_sizes[0] / 4;
    int E = in_sizes[1] / 2;
    const int* src = ei;
    const int* dst = ei + E;

    char* ws = (char*)d_ws;
    size_t off_b = 0;
    auto alloc = [&](size_t bytes)->void*{
        void* p = ws + off_b;
        off_b += (bytes + 255) & ~(size_t)255;
        return p;
    };
    unsigned char* xw1  = (unsigned char*)alloc((size_t)N * 64);  // fp8 e4m3
    unsigned char* h1f8 = (unsigned char*)alloc((size_t)N * 64);  // fp8 e4m3 h1
    uint2*    asvb   = (uint2*)alloc((size_t)N * 8);              // bf16x4 alpha_src
    float*    adv    = (float*)alloc((size_t)N * 4 * 4);
    float*    adv2   = (float*)alloc((size_t)N * 4 * 4);
    int*      gcnt   = (int*)alloc((size_t)MAXBUK * 4);           // per-bucket fill count
    unsigned* staged = (unsigned*)alloc((size_t)MAXBUK * CAP * 4);// slab: src | localdst<<17
    int2*     offp   = (int2*)alloc((size_t)N * 8);               // per-dst (start,end)
    int*      csr    = (int*)alloc((size_t)MAXBUK * CAP * 4);     // slab csr
    float*    xw2    = (float*)alloc((size_t)N * 8 * 4);
    float*    pool   = (float*)alloc(64 * 8 * 4);

    int nbuk = (N + BSZ - 1) / BSZ;          // 447
    int chunksz = (E + NBIN - 1) / NBIN;     // 6250 <= LSTG

    hipMemsetAsync(pool, 0, 64 * 8 * 4, stream);
    hipMemsetAsync(gcnt, 0, (size_t)MAXBUK * 4, stream);

    // slab binning (LDS-staged, int4 edge loops, full-line flush) + per-bucket local sort
    k_bin2<<<NBIN, 1024, 0, stream>>>(src, dst, gcnt, staged, E, chunksz, nbuk);
    k_l1_node<<<(N + 255) / 256, 256, 0, stream>>>(x, W1, as1, ad1, xw1, asvb, adv, N);
    k_local<<<nbuk, 1024, 0, stream>>>(staged, gcnt, offp, csr, N);

    // layer 1 gather (4-deep batch + fold-reduce + distributed epilogue -> h1 fp8)
    k_l1_gather<<<(int)(((long)N * 64 + 255) / 256), 256, 0, stream>>>(
        offp, csr, asvb, adv, xw1, b1, h1f8, N);
    // dense layer-2 node transform (packed)
    k_l2_node<<<(N + 255) / 256, 256, 0, stream>>>(h1f8, W2, ad2, xw2, adv2, N);
    // layer 2 gather + fused mean pool
    k_l2_gather<<<(int)(((long)N * 64 + 255) / 256), 256, 0, stream>>>(
        offp, csr, adv2, xw2, b2, as2, pool, N);
    // head
    k_final<<<1, 64, 0, stream>>>(pool, Wout, bout, out, 1.0f / (float)N);
}

// Round 13
// 161.539 us; speedup vs baseline: 1.0977x; 1.0003x over previous
//
#include <hip/hip_runtime.h>
#include <hip/hip_fp8.h>

#define NEG 0.2f
#define BSZ 224          // nodes per dst bucket
#define MAXBUK 512       // >= ceil(N/BSZ) = 447
#define NBIN 512         // binning blocks
#define CAP 16384        // slab capacity per bucket
#define LSTG 6400        // bin2 LDS staging entries (>= chunksz = 6250)
#define LSLAB 11264      // k_local LDS slab entries (gcnt max ~10.7K, +7 sigma)

typedef float v2f __attribute__((ext_vector_type(2)));

__device__ __forceinline__ float elufast(float x){ return x > 0.0f ? x : __expf(x) - 1.0f; }
__device__ __forceinline__ float b2f(unsigned short b){ return __uint_as_float((unsigned)b << 16); }
__device__ __forceinline__ unsigned short f2b(float x){
    unsigned u = __float_as_uint(x);
    return (unsigned short)((u + 0x7FFFu + ((u >> 16) & 1u)) >> 16);   // RNE
}

// decode 8 fp8-e4m3 (uint2) via HW v_cvt_pk_f32_fp8, accumulate with packed fma (v_pk_fma_f32)
__device__ __forceinline__ void fma8(uint2 r, float w, v2f* acc){
    v2f w2 = {w, w};
    v2f f0 = __builtin_amdgcn_cvt_pk_f32_fp8(r.x, false);
    v2f f1 = __builtin_amdgcn_cvt_pk_f32_fp8(r.x, true);
    v2f f2 = __builtin_amdgcn_cvt_pk_f32_fp8(r.y, false);
    v2f f3 = __builtin_amdgcn_cvt_pk_f32_fp8(r.y, true);
    acc[0] = __builtin_elementwise_fma(f0, w2, acc[0]);
    acc[1] = __builtin_elementwise_fma(f1, w2, acc[1]);
    acc[2] = __builtin_elementwise_fma(f2, w2, acc[2]);
    acc[3] = __builtin_elementwise_fma(f3, w2, acc[3]);
}

// ---- layer 1 node transform (packed v2f): xw1(fp8)[N,64], asvb(bf16x4)[N], adv[N,4] ----
__global__ void k_l1_node(const float* __restrict__ x, const float* __restrict__ W1,
                          const float* __restrict__ as1, const float* __restrict__ ad1,
                          unsigned char* __restrict__ xw1, uint2* __restrict__ asvb,
                          float* __restrict__ adv, int N){
    __shared__ float sW[256], sA[64], sD[64];
    int tid = threadIdx.x;
    sW[tid] = W1[tid];
    if (tid < 64){ sA[tid] = as1[tid]; sD[tid] = ad1[tid]; }
    __syncthreads();
    int i = blockIdx.x * 256 + tid;
    if (i >= N) return;
    float4 xv = ((const float4*)x)[i];
    const v2f* sW0 = (const v2f*)sW;
    const v2f* sW1v = (const v2f*)(sW + 64);
    const v2f* sW2v = (const v2f*)(sW + 128);
    const v2f* sW3v = (const v2f*)(sW + 192);
    v2f xx = {xv.x, xv.x}, yy = {xv.y, xv.y}, zz = {xv.z, xv.z}, ww = {xv.w, xv.w};
    v2f xwv[32];
    #pragma unroll
    for (int j = 0; j < 32; j++){
        v2f t = xx * sW0[j];
        t = __builtin_elementwise_fma(yy, sW1v[j], t);
        t = __builtin_elementwise_fma(zz, sW2v[j], t);
        t = __builtin_elementwise_fma(ww, sW3v[j], t);
        xwv[j] = t;
    }
    unsigned wv[16];
    #pragma unroll
    for (int j = 0; j < 16; j++){
        unsigned p = 0;
        p = __builtin_amdgcn_cvt_pk_fp8_f32(xwv[2 * j].x,     xwv[2 * j].y,     p, false);
        p = __builtin_amdgcn_cvt_pk_fp8_f32(xwv[2 * j + 1].x, xwv[2 * j + 1].y, p, true);
        wv[j] = p;
    }
    uint4* dp = (uint4*)(xw1 + (size_t)i * 64);
    dp[0] = make_uint4(wv[0],  wv[1],  wv[2],  wv[3]);
    dp[1] = make_uint4(wv[4],  wv[5],  wv[6],  wv[7]);
    dp[2] = make_uint4(wv[8],  wv[9],  wv[10], wv[11]);
    dp[3] = make_uint4(wv[12], wv[13], wv[14], wv[15]);
    const v2f* sAv = (const v2f*)sA;
    const v2f* sDv = (const v2f*)sD;
    float al[4];
    #pragma unroll
    for (int h = 0; h < 4; h++){
        v2f asv = {0.f, 0.f}, adw = {0.f, 0.f};
        #pragma unroll
        for (int c2 = 0; c2 < 8; c2++){
            asv = __builtin_elementwise_fma(xwv[h * 8 + c2], sAv[h * 8 + c2], asv);
            adw = __builtin_elementwise_fma(xwv[h * 8 + c2], sDv[h * 8 + c2], adw);
        }
        al[h] = asv.x + asv.y;
        adv[i * 4 + h] = adw.x + adw.y;
    }
    asvb[i] = make_uint2((unsigned)f2b(al[0]) | ((unsigned)f2b(al[1]) << 16),
                         (unsigned)f2b(al[2]) | ((unsigned)f2b(al[3]) << 16));
}

// ---- slab binning: LDS staging, int4 loops, 2x-replicated hist/cursor (halved LDS-atomic
// contention), full-line flush. Slab b: [b*CAP, b*CAP+gcnt[b]); pad = sentinel ----
__global__ void k_bin2(const int* __restrict__ src, const int* __restrict__ dst,
                       int* __restrict__ gcnt, unsigned* __restrict__ staged,
                       int E, int chunksz, int nbuk){
    __shared__ int histA[MAXBUK], histB[MAXBUK];
    __shared__ int curA[MAXBUK], curB[MAXBUK];
    __shared__ int lsb[MAXBUK];     // local start in lstg
    __shared__ int gbase[MAXBUK];   // reserved global base (64B aligned)
    __shared__ int ts[512];
    __shared__ unsigned lstg[LSTG]; // block-local sorted edges (~25 KB)
    int tid = threadIdx.x;
    int half = tid >> 9;            // 0 for tid<512, 1 for tid>=512
    int* hist = half ? histB : histA;
    for (int b = tid; b < MAXBUK; b += 1024){ histA[b] = 0; histB[b] = 0; }
    __syncthreads();
    int e0 = blockIdx.x * chunksz, e1 = min(E, e0 + chunksz);
    int a0 = min(e1, (e0 + 3) & ~3);         // aligned start
    int a1 = max(a0, e1 & ~3);               // aligned end
    // ---- pass 1: count into half-private hist (head / int4 body / tail) ----
    if (tid < a0 - e0) atomicAdd(&hist[(unsigned)dst[e0 + tid] / BSZ], 1);
    for (int q = (a0 >> 2) + tid; q < (a1 >> 2); q += 1024){
        int4 d4 = ((const int4*)dst)[q];
        atomicAdd(&hist[(unsigned)d4.x / BSZ], 1);
        atomicAdd(&hist[(unsigned)d4.y / BSZ], 1);
        atomicAdd(&hist[(unsigned)d4.z / BSZ], 1);
        atomicAdd(&hist[(unsigned)d4.w / BSZ], 1);
    }
    if (tid < e1 - a1) atomicAdd(&hist[(unsigned)dst[a1 + tid] / BSZ], 1);
    __syncthreads();
    int v = 0, hA = 0;
    if (tid < 512){ hA = histA[tid]; v = hA + histB[tid]; ts[tid] = v; }
    __syncthreads();
    for (int s = 1; s < 512; s <<= 1){                   // scan local totals
        int tmp = (tid >= s && tid < 512) ? ts[tid - s] : 0;
        __syncthreads();
        if (tid < 512) ts[tid] += tmp;
        __syncthreads();
    }
    if (tid < 512){
        int excl = ts[tid] - v;
        lsb[tid] = excl;
        curA[tid] = excl;                                // half 0 writes [excl, excl+hA)
        curB[tid] = excl + hA;                           // half 1 writes after
        int padded = (v + 15) & ~15;                     // 64B multiple
        gbase[tid] = tid * CAP + (padded ? atomicAdd(&gcnt[tid], padded) : 0);
    }
    __syncthreads();
    // ---- pass 2: scatter into LDS via half-private cursor ----
    int* cur = half ? curB : curA;
    auto put = [&](int d, int s){
        int buk = (unsigned)d / BSZ;
        int pos = atomicAdd(&cur[buk], 1);
        lstg[pos] = (unsigned)s | ((unsigned)(d - buk * BSZ) << 17);
    };
    if (tid < a0 - e0) put(dst[e0 + tid], src[e0 + tid]);
    for (int q = (a0 >> 2) + tid; q < (a1 >> 2); q += 1024){
        int4 d4 = ((const int4*)dst)[q];
        int4 s4 = ((const int4*)src)[q];
        put(d4.x, s4.x); put(d4.y, s4.y); put(d4.z, s4.z); put(d4.w, s4.w);
    }
    if (tid < e1 - a1) put(dst[a1 + tid], src[a1 + tid]);
    __syncthreads();
    // ---- flush: wave w owns buckets w, w+16, ... — contiguous full-line bursts ----
    int wv = tid >> 6, ln = tid & 63;
    for (int b = wv; b < nbuk; b += 16){
        int cnt = histA[b] + histB[b];
        int padded = (cnt + 15) & ~15;
        int lb = lsb[b], gb = gbase[b];
        for (int j = ln; j < padded; j += 64)
            staged[gb + j] = (j < cnt) ? lstg[lb + j] : 0xFFFFFFFFu;
    }
}

// ---- per-bucket local sort: ONE global pass (uint4 load fused with count -> LDS slab),
// scatter from LDS. Slab ranges 16-entry aligned. ----
__global__ void k_local(const unsigned* __restrict__ staged, const int* __restrict__ gcnt,
                        int2* __restrict__ offp, int* __restrict__ csr, int N){
    __shared__ unsigned lslab[LSLAB];
    __shared__ int deg[BSZ];
    __shared__ int cur[BSZ];
    __shared__ int ts[256];
    int b = blockIdx.x, t = threadIdx.x;
    int lo = b * BSZ, hi = min(N, lo + BSZ);
    int e0 = b * CAP;
    int cnt = min(gcnt[b], LSLAB);           // multiple of 16; clamp = memory safety
    if (t < BSZ) deg[t] = 0;
    __syncthreads();
    // fused: load slab into LDS + count degrees (single global pass)
    for (int q = t; q < (cnt >> 2); q += 1024){
        uint4 s4 = ((const uint4*)(staged + e0))[q];
        ((uint4*)lslab)[q] = s4;
        if (s4.x != 0xFFFFFFFFu) atomicAdd(&deg[s4.x >> 17], 1);
        if (s4.y != 0xFFFFFFFFu) atomicAdd(&deg[s4.y >> 17], 1);
        if (s4.z != 0xFFFFFFFFu) atomicAdd(&deg[s4.z >> 17], 1);
        if (s4.w != 0xFFFFFFFFu) atomicAdd(&deg[s4.w >> 17], 1);
    }
    __syncthreads();
    int v = 0;
    if (t < 256){
        v = (t < BSZ) ? deg[t] : 0;
        ts[t] = v;
    }
    __syncthreads();
    for (int s = 1; s < 256; s <<= 1){            // 256-lane Hillis-Steele; others barrier-only
        int tmp = (t >= s && t < 256) ? ts[t - s] : 0;
        __syncthreads();
        if (t < 256) ts[t] += tmp;
        __syncthreads();
    }
    if (t < BSZ){
        cur[t] = e0 + ts[t] - v;
        if (lo + t < hi) offp[lo + t] = make_int2(e0 + ts[t] - v, e0 + ts[t]);
    }
    __syncthreads();
    // scatter from LDS to csr (writes land in one contiguous ~cnt*4B region)
    for (int e = t; e < cnt; e += 1024){
        unsigned se = lslab[e];
        if (se == 0xFFFFFFFFu) continue;
        int pos = atomicAdd(&cur[se >> 17], 1);
        csr[pos] = (int)(se & 0x1FFFFu);
    }
}

// ---- layer 1 gather: 4-deep batch + fold-reduce + distributed epilogue ----
// wave per dst; lane = (edge slot g=lane>>3, chan oct q=lane&7), head h=q>>1.
__global__ void k_l1_gather(const int2* __restrict__ offp, const int* __restrict__ csr,
                            const uint2* __restrict__ asvb, const float* __restrict__ adv,
                            const unsigned char* __restrict__ xw1, const float* __restrict__ b1,
                            unsigned char* __restrict__ h1f8, int N){
    int tid = threadIdx.x;
    int wid = (int)(((long)blockIdx.x * 256 + tid) >> 6);
    if (wid >= N) return;
    int lane = tid & 63;
    int g = lane >> 3;          // edge slot 0..7
    int q = lane & 7;           // channel oct: channels q*8 .. q*8+7
    int h = q >> 1;             // head
    float advd = adv[wid * 4 + h];
    const unsigned char* xwq = xw1 + q * 8;                 // per-lane row base
    const char* asvbh = (const char*)asvb + h * 2;          // per-lane bf16 slot

    v2f acc2[4] = {{0.f, 0.f}, {0.f, 0.f}, {0.f, 0.f}, {0.f, 0.f}};
    float den = 0.f;
    int2 rng = offp[wid];
    int k = rng.x, end = rng.y;
    for (; k + 32 <= end; k += 32){         // 4 batches of 8 edges: all loads in flight
        int s0 = csr[k + g];
        int s1 = csr[k + 8 + g];
        int s2 = csr[k + 16 + g];
        int s3 = csr[k + 24 + g];
        uint2 r0 = *(const uint2*)(xwq + ((size_t)s0 << 6));
        uint2 r1 = *(const uint2*)(xwq + ((size_t)s1 << 6));
        uint2 r2 = *(const uint2*)(xwq + ((size_t)s2 << 6));
        uint2 r3 = *(const uint2*)(xwq + ((size_t)s3 << 6));
        float a0 = b2f(*(const unsigned short*)(asvbh + ((size_t)s0 << 3)));
        float a1 = b2f(*(const unsigned short*)(asvbh + ((size_t)s1 << 3)));
        float a2 = b2f(*(const unsigned short*)(asvbh + ((size_t)s2 << 3)));
        float a3 = b2f(*(const unsigned short*)(asvbh + ((size_t)s3 << 3)));
        float t0 = a0 + advd, t1 = a1 + advd, t2 = a2 + advd, t3 = a3 + advd;
        float w0 = __expf(fmaxf(t0, NEG * t0));
        float w1 = __expf(fmaxf(t1, NEG * t1));
        float w2 = __expf(fmaxf(t2, NEG * t2));
        float w3 = __expf(fmaxf(t3, NEG * t3));
        den += (w0 + w1) + (w2 + w3);
        fma8(r0, w0, acc2);
        fma8(r1, w1, acc2);
        fma8(r2, w2, acc2);
        fma8(r3, w3, acc2);
    }
    if (k + 16 <= end){                     // 2-batch step
        int sA = csr[k + g];
        int sB = csr[k + 8 + g];
        uint2 rA = *(const uint2*)(xwq + ((size_t)sA << 6));
        uint2 rB = *(const uint2*)(xwq + ((size_t)sB << 6));
        float aA = b2f(*(const unsigned short*)(asvbh + ((size_t)sA << 3)));
        float aB = b2f(*(const unsigned short*)(asvbh + ((size_t)sB << 3)));
        float tA = aA + advd, tB = aB + advd;
        float wA = __expf(fmaxf(tA, NEG * tA));
        float wB = __expf(fmaxf(tB, NEG * tB));
        den += wA + wB;
        fma8(rA, wA, acc2);
        fma8(rB, wB, acc2);
        k += 16;
    }
    for (; k < end; k += 8){                // masked tail
        int e = k + g;
        bool valid = e < end;
        int s = csr[valid ? e : end - 1];
        uint2 r = *(const uint2*)(xwq + ((size_t)s << 6));
        float a = b2f(*(const unsigned short*)(asvbh + ((size_t)s << 3)));
        float t = a + advd;
        float w = valid ? __expf(fmaxf(t, NEG * t)) : 0.f;
        den += w;
        fma8(r, w, acc2);
    }

    // ---- fold-reduce across the 8 edge slots (lane bits 3..5), keep-half per stage ----
    v2f t0, t1, t2, t3;
    t0.x = __shfl_xor(acc2[0].x, 32); t0.y = __shfl_xor(acc2[0].y, 32);
    t1.x = __shfl_xor(acc2[1].x, 32); t1.y = __shfl_xor(acc2[1].y, 32);
    t2.x = __shfl_xor(acc2[2].x, 32); t2.y = __shfl_xor(acc2[2].y, 32);
    t3.x = __shfl_xor(acc2[3].x, 32); t3.y = __shfl_xor(acc2[3].y, 32);
    bool gb2 = (lane & 32) != 0;                 // g bit2
    v2f n0 = gb2 ? (acc2[2] + t2) : (acc2[0] + t0);   // keep half holding my channel pair
    v2f n1 = gb2 ? (acc2[3] + t3) : (acc2[1] + t1);
    v2f u0, u1;
    u0.x = __shfl_xor(n0.x, 16); u0.y = __shfl_xor(n0.y, 16);
    u1.x = __shfl_xor(n1.x, 16); u1.y = __shfl_xor(n1.y, 16);
    bool gb1 = (lane & 16) != 0;                 // g bit1
    v2f rr = gb1 ? (n1 + u1) : (n0 + u0);
    v2f z;
    z.x = __shfl_xor(rr.x, 8); z.y = __shfl_xor(rr.y, 8);
    rr += z;                                     // summed over all 8 slots
    bool gb0 = (lane & 8) != 0;                  // g bit0 -> component
    den += __shfl_xor(den, 8);
    den += __shfl_xor(den, 16);
    den += __shfl_xor(den, 32);
    float val = gb0 ? rr.y : rr.x;               // total for channel c = q*8+g

    // ---- distributed epilogue: all 64 lanes; lane (g,q) owns channel c=q*8+g ----
    int c = q * 8 + g;
    float aself = b2f(*(const unsigned short*)(asvbh + ((size_t)wid << 3)));
    float tsv = aself + advd;
    float ws = __expf(fmaxf(tsv, NEG * tsv));               // self-loop weight (per head)
    unsigned selfb = xw1[(size_t)wid * 64 + c];             // coalesced byte load
    v2f sf = __builtin_amdgcn_cvt_pk_f32_fp8(selfb, false); // sf.x = fp8(byte0)
    float asel = val + ws * sf.x;
    float inv = 1.0f / (den + ws + 1e-16f);
    float o = elufast(asel * inv + b1[c]);
    unsigned p = __builtin_amdgcn_cvt_pk_fp8_f32(o, o, 0, false);
    h1f8[(size_t)wid * 64 + c] = (unsigned char)p;          // coalesced byte store
}

// ---- layer 2 node transform (packed v2f + b64 LDS reads): xw2[N,8], adv2[N,4] ----
__global__ void k_l2_node(const unsigned char* __restrict__ h1f8, const float* __restrict__ W2,
                          const float* __restrict__ ad2, float* __restrict__ xw2,
                          float* __restrict__ adv2, int N){
    __shared__ float sW[512], sD[8];
    int tid = threadIdx.x;
    sW[tid] = W2[tid];
    sW[256 + tid] = W2[256 + tid];
    if (tid < 8) sD[tid] = ad2[tid];
    __syncthreads();
    int i = blockIdx.x * 256 + tid;
    if (i >= N) return;
    const uint2* rp = (const uint2*)(h1f8 + (size_t)i * 64);
    v2f acc2[4] = {{0.f, 0.f}, {0.f, 0.f}, {0.f, 0.f}, {0.f, 0.f}};
    #pragma unroll
    for (int b8 = 0; b8 < 8; b8++){
        uint2 r = rp[b8];
        v2f f0 = __builtin_amdgcn_cvt_pk_f32_fp8(r.x, false);
        v2f f1 = __builtin_amdgcn_cvt_pk_f32_fp8(r.x, true);
        v2f f2 = __builtin_amdgcn_cvt_pk_f32_fp8(r.y, false);
        v2f f3 = __builtin_amdgcn_cvt_pk_f32_fp8(r.y, true);
        float f[8] = {f0.x, f0.y, f1.x, f1.y, f2.x, f2.y, f3.x, f3.y};
        #pragma unroll
        for (int j = 0; j < 8; j++){
            v2f hcv = {f[j], f[j]};
            const v2f* wrow = (const v2f*)&sW[(b8 * 8 + j) * 8];   // broadcast b64 reads
            acc2[0] = __builtin_elementwise_fma(hcv, wrow[0], acc2[0]);
            acc2[1] = __builtin_elementwise_fma(hcv, wrow[1], acc2[1]);
            acc2[2] = __builtin_elementwise_fma(hcv, wrow[2], acc2[2]);
            acc2[3] = __builtin_elementwise_fma(hcv, wrow[3], acc2[3]);
        }
    }
    float4* xo = (float4*)(xw2 + (size_t)i * 8);
    xo[0] = make_float4(acc2[0].x, acc2[0].y, acc2[1].x, acc2[1].y);
    xo[1] = make_float4(acc2[2].x, acc2[2].y, acc2[3].x, acc2[3].y);
    float4 dv;
    dv.x = acc2[0].x * sD[0] + acc2[0].y * sD[1];
    dv.y = acc2[1].x * sD[2] + acc2[1].y * sD[3];
    dv.z = acc2[2].x * sD[4] + acc2[2].y * sD[5];
    dv.w = acc2[3].x * sD[6] + acc2[3].y * sD[7];
    *(float4*)(adv2 + (size_t)i * 4) = dv;
}

// ---- layer 2 gather: lane = (edge slot g=lane>>2 0..15, head hh=lane&3) ----
__global__ void k_l2_gather(const int2* __restrict__ offp, const int* __restrict__ csr,
                            const float* __restrict__ adv2, const float* __restrict__ xw2,
                            const float* __restrict__ b2, const float* __restrict__ as2,
                            float* __restrict__ pool, int N){
    __shared__ float lpool[8];
    int tid = threadIdx.x;
    if (tid < 8) lpool[tid] = 0.f;
    __syncthreads();
    int wid = (int)(((long)blockIdx.x * 256 + tid) >> 6);
    if (wid < N){
        int lane = tid & 63;
        int g = lane >> 2;          // edge slot 0..15
        int hh = lane & 3;          // head
        float2 a2h = *(const float2*)&as2[hh * 2];
        float advd = adv2[wid * 4 + hh];
        const char* xwh = (const char*)xw2 + hh * 8;
        v2f accv = {0.f, 0.f};
        float den = 0.f;

        auto edge = [&](int s, bool valid){
            v2f v = *(const v2f*)(xwh + ((size_t)s << 5));
            float al = v.x * a2h.x + v.y * a2h.y;
            float t = al + advd;
            float w = valid ? __expf(fmaxf(t, NEG * t)) : 0.f;
            den += w;
            v2f w2 = {w, w};
            accv = __builtin_elementwise_fma(v, w2, accv);
        };

        int2 rng = offp[wid];
        int k = rng.x, end = rng.y;
        for (; k + 32 <= end; k += 32){     // 2 batches of 16 edges in flight
            int s0 = csr[k + g], s1 = csr[k + 16 + g];
            edge(s0, true); edge(s1, true);
        }
        for (; k < end; k += 16){           // masked tail
            int e = k + g;
            bool valid = e < end;
            int s = csr[valid ? e : end - 1];
            edge(s, valid);
        }
        // reduce over edge slots (lane bits 2..5)
        #pragma unroll
        for (int m = 4; m <= 32; m <<= 1){
            accv.x += __shfl_xor(accv.x, m);
            accv.y += __shfl_xor(accv.y, m);
            den    += __shfl_xor(den, m);
        }
        if (g == 0){                         // lanes 0..3, lane hh owns head hh
            v2f v = *(const v2f*)(xwh + ((size_t)wid << 5));
            float al = v.x * a2h.x + v.y * a2h.y;
            float t = al + advd;
            float ws = __expf(fmaxf(t, NEG * t));
            den += ws;
            accv.x += ws * v.x;
            accv.y += ws * v.y;
            float inv = 1.0f / (den + 1e-16f);
            float o0 = elufast(accv.x * inv + b2[hh * 2]);
            float o1 = elufast(accv.y * inv + b2[hh * 2 + 1]);
            atomicAdd(&lpool[hh * 2], o0);
            atomicAdd(&lpool[hh * 2 + 1], o1);
        }
    }
    __syncthreads();
    if (tid < 8) atomicAdd(&pool[(blockIdx.x & 63) * 8 + tid], lpool[tid]);
}

// ---- output head: reduce 64x8 pool partials, apply mean+W+sigmoid ----
__global__ void k_final(const float* __restrict__ pool, const float* __restrict__ Wout,
                        const float* __restrict__ bout, float* __restrict__ out, float invN){
    int lane = threadIdx.x;      // 64 lanes, lane l owns slot l
    const float4* p4 = (const float4*)(pool + lane * 8);
    float4 a = p4[0], b = p4[1];
    float v[8] = {a.x, a.y, a.z, a.w, b.x, b.y, b.z, b.w};
    #pragma unroll
    for (int m = 1; m <= 32; m <<= 1){
        #pragma unroll
        for (int j = 0; j < 8; j++) v[j] += __shfl_xor(v[j], m);
    }
    if (lane == 0){
        float z = bout[0];
        #pragma unroll
        for (int j = 0; j < 8; j++) z += v[j] * invN * Wout[j];
        out[0] = 1.0f / (1.0f + __expf(-z));
    }
}

extern "C" void kernel_launch(void* const* d_in, const int* in_sizes, int n_in,
                              void* d_out, int out_size, void* d_ws, size_t ws_size,
                              hipStream_t stream){
    const float* x    = (const float*)d_in[0];
    const int*   ei   = (const int*)d_in[1];     // int32
    const float* W1   = (const float*)d_in[2];
    const float* as1  = (const float*)d_in[3];
    const float* ad1  = (const float*)d_in[4];
    const float* b1   = (const float*)d_in[5];
    const float* W2   = (const float*)d_in[6];
    const float* as2  = (const float*)d_in[7];
    const float* ad2  = (const float*)d_in[8];
    const float* b2   = (const float*)d_in[9];
    const float* Wout = (const float*)d_in[10];
    const float* bout = (const float*)d_in[11];
    float* out = (float*)d_out;

    int N = in_sizes[0] / 4;
    int E = in_sizes[1] / 2;
    const int* src = ei;
    const int* dst = ei + E;

    char* ws = (char*)d_ws;
    size_t off_b = 0;
    auto alloc = [&](size_t bytes)->void*{
        void* p = ws + off_b;
        off_b += (bytes + 255) & ~(size_t)255;
        return p;
    };
    unsigned char* xw1  = (unsigned char*)alloc((size_t)N * 64);  // fp8 e4m3
    unsigned char* h1f8 = (unsigned char*)alloc((size_t)N * 64);  // fp8 e4m3 h1
    uint2*    asvb   = (uint2*)alloc((size_t)N * 8);              // bf16x4 alpha_src
    float*    adv    = (float*)alloc((size_t)N * 4 * 4);
    float*    adv2   = (float*)alloc((size_t)N * 4 * 4);
    int*      gcnt   = (int*)alloc((size_t)MAXBUK * 4);           // per-bucket fill count
    unsigned* staged = (unsigned*)alloc((size_t)MAXBUK * CAP * 4);// slab: src | localdst<<17
    int2*     offp   = (int2*)alloc((size_t)N * 8);               // per-dst (start,end)
    int*      csr    = (int*)alloc((size_t)MAXBUK * CAP * 4);     // slab csr
    float*    xw2    = (float*)alloc((size_t)N * 8 * 4);
    float*    pool   = (float*)alloc(64 * 8 * 4);

    int nbuk = (N + BSZ - 1) / BSZ;          // 447
    int chunksz = (E + NBIN - 1) / NBIN;     // 6250 <= LSTG

    hipMemsetAsync(pool, 0, 64 * 8 * 4, stream);
    hipMemsetAsync(gcnt, 0, (size_t)MAXBUK * 4, stream);

    // slab binning (LDS-staged, replicated hist, full-line flush) + one-pass local sort
    k_bin2<<<NBIN, 1024, 0, stream>>>(src, dst, gcnt, staged, E, chunksz, nbuk);
    k_l1_node<<<(N + 255) / 256, 256, 0, stream>>>(x, W1, as1, ad1, xw1, asvb, adv, N);
    k_local<<<nbuk, 1024, 0, stream>>>(staged, gcnt, offp, csr, N);

    // layer 1 gather (4-deep batch + fold-reduce + distributed epilogue -> h1 fp8)
    k_l1_gather<<<(int)(((long)N * 64 + 255) / 256), 256, 0, stream>>>(
        offp, csr, asvb, adv, xw1, b1, h1f8, N);
    // dense layer-2 node transform (packed)
    k_l2_node<<<(N + 255) / 256, 256, 0, stream>>>(h1f8, W2, ad2, xw2, adv2, N);
    // layer 2 gather + fused mean pool
    k_l2_gather<<<(int)(((long)N * 64 + 255) / 256), 256, 0, stream>>>(
        offp, csr, adv2, xw2, b2, as2, pool, N);
    // head
    k_final<<<1, 64, 0, stream>>>(pool, Wout, bout, out, 1.0f / (float)N);
}

// Round 14
// 160.633 us; speedup vs baseline: 1.1038x; 1.0056x over previous
//
#include <hip/hip_runtime.h>
#include <hip/hip_fp8.h>

#define NEG 0.2f
#define BSZ 224          // nodes per dst bucket
#define MAXBUK 512       // >= ceil(N/BSZ) = 447
#define NBIN 512         // binning blocks
#define CAP 16384        // slab capacity per bucket
#define LSTG 6400        // bin2 LDS staging entries (>= chunksz = 6250)
#define LSLAB 11264      // k_local LDS slab entries (gcnt max ~10.7K, +7 sigma)

typedef float v2f __attribute__((ext_vector_type(2)));

__device__ __forceinline__ float elufast(float x){ return x > 0.0f ? x : __expf(x) - 1.0f; }
__device__ __forceinline__ float b2f(unsigned short b){ return __uint_as_float((unsigned)b << 16); }
__device__ __forceinline__ unsigned short f2b(float x){
    unsigned u = __float_as_uint(x);
    return (unsigned short)((u + 0x7FFFu + ((u >> 16) & 1u)) >> 16);   // RNE
}

// decode 8 fp8-e4m3 (uint2) via HW v_cvt_pk_f32_fp8, accumulate with packed fma (v_pk_fma_f32)
__device__ __forceinline__ void fma8(uint2 r, float w, v2f* acc){
    v2f w2 = {w, w};
    v2f f0 = __builtin_amdgcn_cvt_pk_f32_fp8(r.x, false);
    v2f f1 = __builtin_amdgcn_cvt_pk_f32_fp8(r.x, true);
    v2f f2 = __builtin_amdgcn_cvt_pk_f32_fp8(r.y, false);
    v2f f3 = __builtin_amdgcn_cvt_pk_f32_fp8(r.y, true);
    acc[0] = __builtin_elementwise_fma(f0, w2, acc[0]);
    acc[1] = __builtin_elementwise_fma(f1, w2, acc[1]);
    acc[2] = __builtin_elementwise_fma(f2, w2, acc[2]);
    acc[3] = __builtin_elementwise_fma(f3, w2, acc[3]);
}

// ---- FUSED: slab binning (idle-heavy) + layer-1 node transform (VALU-heavy) ----
// Block roles Bresenham-interleaved across blockIdx so both kinds co-reside per CU:
// bin blocks stall on latency/barriers while node blocks consume the idle issue slots.
// Node role: 1024 threads, 2 threads per node (half = 32 channels, 2 heads each)
// to keep VGPR <= 64 at 32 waves/CU.
__global__ __launch_bounds__(1024, 8)
void k_bin_node(const int* __restrict__ src, const int* __restrict__ dst,
                int* __restrict__ gcnt, unsigned* __restrict__ staged,
                const float* __restrict__ x, const float* __restrict__ W1,
                const float* __restrict__ as1, const float* __restrict__ ad1,
                unsigned char* __restrict__ xw1, unsigned* __restrict__ asvb32,
                float* __restrict__ adv,
                int E, int chunksz, int nbuk, int N, int nnodeblk, int grid){
    __shared__ int histA[MAXBUK], histB[MAXBUK];
    __shared__ int curA[MAXBUK], curB[MAXBUK];
    __shared__ int lsb[MAXBUK];
    __shared__ int gbase[MAXBUK];
    __shared__ int ts[512];
    __shared__ unsigned lstg[LSTG];
    __shared__ float sW[256], sA[64], sD[64];
    int r = blockIdx.x;
    int nodeBefore = (int)(((long)r * nnodeblk) / grid);
    int isNode = (int)(((long)(r + 1) * nnodeblk) / grid) > nodeBefore;
    int tid = threadIdx.x;

    if (isNode){
        // ---------- node-transform role (block nodeBefore) ----------
        if (tid < 256) sW[tid] = W1[tid];
        else if (tid < 320) sA[tid - 256] = as1[tid - 256];
        else if (tid < 384) sD[tid - 320] = ad1[tid - 320];
        __syncthreads();
        int half = tid & 1;                       // channels half*32..+31, heads half*2, half*2+1
        int i = nodeBefore * 512 + (tid >> 1);
        if (i >= N) return;
        float4 xv = ((const float4*)x)[i];
        const v2f* r0 = (const v2f*)(sW      ) + half * 16;
        const v2f* r1 = (const v2f*)(sW + 64 ) + half * 16;
        const v2f* r2 = (const v2f*)(sW + 128) + half * 16;
        const v2f* r3 = (const v2f*)(sW + 192) + half * 16;
        v2f xx = {xv.x, xv.x}, yy = {xv.y, xv.y}, zz = {xv.z, xv.z}, ww = {xv.w, xv.w};
        v2f xwv[16];
        #pragma unroll
        for (int j = 0; j < 16; j++){
            v2f t = xx * r0[j];
            t = __builtin_elementwise_fma(yy, r1[j], t);
            t = __builtin_elementwise_fma(zz, r2[j], t);
            t = __builtin_elementwise_fma(ww, r3[j], t);
            xwv[j] = t;
        }
        unsigned wv[8];
        #pragma unroll
        for (int j = 0; j < 8; j++){
            unsigned p = 0;
            p = __builtin_amdgcn_cvt_pk_fp8_f32(xwv[2 * j].x,     xwv[2 * j].y,     p, false);
            p = __builtin_amdgcn_cvt_pk_fp8_f32(xwv[2 * j + 1].x, xwv[2 * j + 1].y, p, true);
            wv[j] = p;
        }
        uint4* dp = (uint4*)(xw1 + (size_t)i * 64 + half * 32);
        dp[0] = make_uint4(wv[0], wv[1], wv[2], wv[3]);
        dp[1] = make_uint4(wv[4], wv[5], wv[6], wv[7]);
        const v2f* sAv = (const v2f*)sA + half * 16;
        const v2f* sDv = (const v2f*)sD + half * 16;
        float al[2], ad_[2];
        #pragma unroll
        for (int hh = 0; hh < 2; hh++){
            v2f asv = {0.f, 0.f}, adw = {0.f, 0.f};
            #pragma unroll
            for (int c2 = 0; c2 < 8; c2++){
                asv = __builtin_elementwise_fma(xwv[hh * 8 + c2], sAv[hh * 8 + c2], asv);
                adw = __builtin_elementwise_fma(xwv[hh * 8 + c2], sDv[hh * 8 + c2], adw);
            }
            al[hh] = asv.x + asv.y;
            ad_[hh] = adw.x + adw.y;
        }
        asvb32[(size_t)i * 2 + half] = (unsigned)f2b(al[0]) | ((unsigned)f2b(al[1]) << 16);
        float2 adpair = {ad_[0], ad_[1]};
        *(float2*)(adv + (size_t)i * 4 + half * 2) = adpair;
        return;
    }

    // ---------- binning role (block bid) ----------
    int bid = r - nodeBefore;
    int half = tid >> 9;            // 0 for tid<512, 1 for tid>=512
    int* hist = half ? histB : histA;
    for (int b = tid; b < MAXBUK; b += 1024){ histA[b] = 0; histB[b] = 0; }
    __syncthreads();
    int e0 = bid * chunksz, e1 = min(E, e0 + chunksz);
    int a0 = min(e1, (e0 + 3) & ~3);         // aligned start
    int a1 = max(a0, e1 & ~3);               // aligned end
    // pass 1: count into half-private hist (head / int4 body / tail)
    if (tid < a0 - e0) atomicAdd(&hist[(unsigned)dst[e0 + tid] / BSZ], 1);
    for (int q = (a0 >> 2) + tid; q < (a1 >> 2); q += 1024){
        int4 d4 = ((const int4*)dst)[q];
        atomicAdd(&hist[(unsigned)d4.x / BSZ], 1);
        atomicAdd(&hist[(unsigned)d4.y / BSZ], 1);
        atomicAdd(&hist[(unsigned)d4.z / BSZ], 1);
        atomicAdd(&hist[(unsigned)d4.w / BSZ], 1);
    }
    if (tid < e1 - a1) atomicAdd(&hist[(unsigned)dst[a1 + tid] / BSZ], 1);
    __syncthreads();
    int v = 0, hA = 0;
    if (tid < 512){ hA = histA[tid]; v = hA + histB[tid]; ts[tid] = v; }
    __syncthreads();
    for (int s = 1; s < 512; s <<= 1){                   // scan local totals
        int tmp = (tid >= s && tid < 512) ? ts[tid - s] : 0;
        __syncthreads();
        if (tid < 512) ts[tid] += tmp;
        __syncthreads();
    }
    if (tid < 512){
        int excl = ts[tid] - v;
        lsb[tid] = excl;
        curA[tid] = excl;                                // half 0 writes [excl, excl+hA)
        curB[tid] = excl + hA;                           // half 1 writes after
        int padded = (v + 15) & ~15;                     // 64B multiple
        gbase[tid] = tid * CAP + (padded ? atomicAdd(&gcnt[tid], padded) : 0);
    }
    __syncthreads();
    // pass 2: scatter into LDS via half-private cursor
    int* cur = half ? curB : curA;
    auto put = [&](int d, int s){
        int buk = (unsigned)d / BSZ;
        int pos = atomicAdd(&cur[buk], 1);
        lstg[pos] = (unsigned)s | ((unsigned)(d - buk * BSZ) << 17);
    };
    if (tid < a0 - e0) put(dst[e0 + tid], src[e0 + tid]);
    for (int q = (a0 >> 2) + tid; q < (a1 >> 2); q += 1024){
        int4 d4 = ((const int4*)dst)[q];
        int4 s4 = ((const int4*)src)[q];
        put(d4.x, s4.x); put(d4.y, s4.y); put(d4.z, s4.z); put(d4.w, s4.w);
    }
    if (tid < e1 - a1) put(dst[a1 + tid], src[a1 + tid]);
    __syncthreads();
    // flush: wave w owns buckets w, w+16, ... — contiguous full-line bursts
    int wvi = tid >> 6, ln = tid & 63;
    for (int b = wvi; b < nbuk; b += 16){
        int cnt = histA[b] + histB[b];
        int padded = (cnt + 15) & ~15;
        int lb = lsb[b], gb = gbase[b];
        for (int j = ln; j < padded; j += 64)
            staged[gb + j] = (j < cnt) ? lstg[lb + j] : 0xFFFFFFFFu;
    }
}

// ---- per-bucket local sort: ONE global pass (uint4 load fused with count -> LDS slab),
// scatter from LDS. Slab ranges 16-entry aligned. ----
__global__ void k_local(const unsigned* __restrict__ staged, const int* __restrict__ gcnt,
                        int2* __restrict__ offp, int* __restrict__ csr, int N){
    __shared__ unsigned lslab[LSLAB];
    __shared__ int deg[BSZ];
    __shared__ int cur[BSZ];
    __shared__ int ts[256];
    int b = blockIdx.x, t = threadIdx.x;
    int lo = b * BSZ, hi = min(N, lo + BSZ);
    int e0 = b * CAP;
    int cnt = min(gcnt[b], LSLAB);           // multiple of 16; clamp = memory safety
    if (t < BSZ) deg[t] = 0;
    __syncthreads();
    for (int q = t; q < (cnt >> 2); q += 1024){
        uint4 s4 = ((const uint4*)(staged + e0))[q];
        ((uint4*)lslab)[q] = s4;
        if (s4.x != 0xFFFFFFFFu) atomicAdd(&deg[s4.x >> 17], 1);
        if (s4.y != 0xFFFFFFFFu) atomicAdd(&deg[s4.y >> 17], 1);
        if (s4.z != 0xFFFFFFFFu) atomicAdd(&deg[s4.z >> 17], 1);
        if (s4.w != 0xFFFFFFFFu) atomicAdd(&deg[s4.w >> 17], 1);
    }
    __syncthreads();
    int v = 0;
    if (t < 256){
        v = (t < BSZ) ? deg[t] : 0;
        ts[t] = v;
    }
    __syncthreads();
    for (int s = 1; s < 256; s <<= 1){            // 256-lane Hillis-Steele; others barrier-only
        int tmp = (t >= s && t < 256) ? ts[t - s] : 0;
        __syncthreads();
        if (t < 256) ts[t] += tmp;
        __syncthreads();
    }
    if (t < BSZ){
        cur[t] = e0 + ts[t] - v;
        if (lo + t < hi) offp[lo + t] = make_int2(e0 + ts[t] - v, e0 + ts[t]);
    }
    __syncthreads();
    for (int e = t; e < cnt; e += 1024){
        unsigned se = lslab[e];
        if (se == 0xFFFFFFFFu) continue;
        int pos = atomicAdd(&cur[se >> 17], 1);
        csr[pos] = (int)(se & 0x1FFFFu);
    }
}

// ---- layer 1 gather: 4-deep batch + fold-reduce + distributed epilogue ----
// wave per dst; lane = (edge slot g=lane>>3, chan oct q=lane&7), head h=q>>1.
__global__ void k_l1_gather(const int2* __restrict__ offp, const int* __restrict__ csr,
                            const uint2* __restrict__ asvb, const float* __restrict__ adv,
                            const unsigned char* __restrict__ xw1, const float* __restrict__ b1,
                            unsigned char* __restrict__ h1f8, int N){
    int tid = threadIdx.x;
    int wid = (int)(((long)blockIdx.x * 256 + tid) >> 6);
    if (wid >= N) return;
    int lane = tid & 63;
    int g = lane >> 3;          // edge slot 0..7
    int q = lane & 7;           // channel oct: channels q*8 .. q*8+7
    int h = q >> 1;             // head
    float advd = adv[wid * 4 + h];
    const unsigned char* xwq = xw1 + q * 8;                 // per-lane row base
    const char* asvbh = (const char*)asvb + h * 2;          // per-lane bf16 slot

    v2f acc2[4] = {{0.f, 0.f}, {0.f, 0.f}, {0.f, 0.f}, {0.f, 0.f}};
    float den = 0.f;
    int2 rng = offp[wid];
    int k = rng.x, end = rng.y;
    for (; k + 32 <= end; k += 32){         // 4 batches of 8 edges: all loads in flight
        int s0 = csr[k + g];
        int s1 = csr[k + 8 + g];
        int s2 = csr[k + 16 + g];
        int s3 = csr[k + 24 + g];
        uint2 r0 = *(const uint2*)(xwq + ((size_t)s0 << 6));
        uint2 r1 = *(const uint2*)(xwq + ((size_t)s1 << 6));
        uint2 r2 = *(const uint2*)(xwq + ((size_t)s2 << 6));
        uint2 r3 = *(const uint2*)(xwq + ((size_t)s3 << 6));
        float a0 = b2f(*(const unsigned short*)(asvbh + ((size_t)s0 << 3)));
        float a1 = b2f(*(const unsigned short*)(asvbh + ((size_t)s1 << 3)));
        float a2 = b2f(*(const unsigned short*)(asvbh + ((size_t)s2 << 3)));
        float a3 = b2f(*(const unsigned short*)(asvbh + ((size_t)s3 << 3)));
        float t0 = a0 + advd, t1 = a1 + advd, t2 = a2 + advd, t3 = a3 + advd;
        float w0 = __expf(fmaxf(t0, NEG * t0));
        float w1 = __expf(fmaxf(t1, NEG * t1));
        float w2 = __expf(fmaxf(t2, NEG * t2));
        float w3 = __expf(fmaxf(t3, NEG * t3));
        den += (w0 + w1) + (w2 + w3);
        fma8(r0, w0, acc2);
        fma8(r1, w1, acc2);
        fma8(r2, w2, acc2);
        fma8(r3, w3, acc2);
    }
    if (k + 16 <= end){                     // 2-batch step
        int sA = csr[k + g];
        int sB = csr[k + 8 + g];
        uint2 rA = *(const uint2*)(xwq + ((size_t)sA << 6));
        uint2 rB = *(const uint2*)(xwq + ((size_t)sB << 6));
        float aA = b2f(*(const unsigned short*)(asvbh + ((size_t)sA << 3)));
        float aB = b2f(*(const unsigned short*)(asvbh + ((size_t)sB << 3)));
        float tA = aA + advd, tB = aB + advd;
        float wA = __expf(fmaxf(tA, NEG * tA));
        float wB = __expf(fmaxf(tB, NEG * tB));
        den += wA + wB;
        fma8(rA, wA, acc2);
        fma8(rB, wB, acc2);
        k += 16;
    }
    for (; k < end; k += 8){                // masked tail
        int e = k + g;
        bool valid = e < end;
        int s = csr[valid ? e : end - 1];
        uint2 r = *(const uint2*)(xwq + ((size_t)s << 6));
        float a = b2f(*(const unsigned short*)(asvbh + ((size_t)s << 3)));
        float t = a + advd;
        float w = valid ? __expf(fmaxf(t, NEG * t)) : 0.f;
        den += w;
        fma8(r, w, acc2);
    }

    // ---- fold-reduce across the 8 edge slots (lane bits 3..5), keep-half per stage ----
    v2f t0, t1, t2, t3;
    t0.x = __shfl_xor(acc2[0].x, 32); t0.y = __shfl_xor(acc2[0].y, 32);
    t1.x = __shfl_xor(acc2[1].x, 32); t1.y = __shfl_xor(acc2[1].y, 32);
    t2.x = __shfl_xor(acc2[2].x, 32); t2.y = __shfl_xor(acc2[2].y, 32);
    t3.x = __shfl_xor(acc2[3].x, 32); t3.y = __shfl_xor(acc2[3].y, 32);
    bool gb2 = (lane & 32) != 0;                 // g bit2
    v2f n0 = gb2 ? (acc2[2] + t2) : (acc2[0] + t0);   // keep half holding my channel pair
    v2f n1 = gb2 ? (acc2[3] + t3) : (acc2[1] + t1);
    v2f u0, u1;
    u0.x = __shfl_xor(n0.x, 16); u0.y = __shfl_xor(n0.y, 16);
    u1.x = __shfl_xor(n1.x, 16); u1.y = __shfl_xor(n1.y, 16);
    bool gb1 = (lane & 16) != 0;                 // g bit1
    v2f rr = gb1 ? (n1 + u1) : (n0 + u0);
    v2f z;
    z.x = __shfl_xor(rr.x, 8); z.y = __shfl_xor(rr.y, 8);
    rr += z;                                     // summed over all 8 slots
    bool gb0 = (lane & 8) != 0;                  // g bit0 -> component
    den += __shfl_xor(den, 8);
    den += __shfl_xor(den, 16);
    den += __shfl_xor(den, 32);
    float val = gb0 ? rr.y : rr.x;               // total for channel c = q*8+g

    // ---- distributed epilogue: all 64 lanes; lane (g,q) owns channel c=q*8+g ----
    int c = q * 8 + g;
    float aself = b2f(*(const unsigned short*)(asvbh + ((size_t)wid << 3)));
    float tsv = aself + advd;
    float ws = __expf(fmaxf(tsv, NEG * tsv));               // self-loop weight (per head)
    unsigned selfb = xw1[(size_t)wid * 64 + c];             // coalesced byte load
    v2f sf = __builtin_amdgcn_cvt_pk_f32_fp8(selfb, false); // sf.x = fp8(byte0)
    float asel = val + ws * sf.x;
    float inv = 1.0f / (den + ws + 1e-16f);
    float o = elufast(asel * inv + b1[c]);
    unsigned p = __builtin_amdgcn_cvt_pk_fp8_f32(o, o, 0, false);
    h1f8[(size_t)wid * 64 + c] = (unsigned char)p;          // coalesced byte store
}

// ---- layer 2 node transform (packed v2f + b64 LDS reads): xw2[N,8], adv2[N,4] ----
__global__ void k_l2_node(const unsigned char* __restrict__ h1f8, const float* __restrict__ W2,
                          const float* __restrict__ ad2, float* __restrict__ xw2,
                          float* __restrict__ adv2, int N){
    __shared__ float sW[512], sD[8];
    int tid = threadIdx.x;
    sW[tid] = W2[tid];
    sW[256 + tid] = W2[256 + tid];
    if (tid < 8) sD[tid] = ad2[tid];
    __syncthreads();
    int i = blockIdx.x * 256 + tid;
    if (i >= N) return;
    const uint2* rp = (const uint2*)(h1f8 + (size_t)i * 64);
    v2f acc2[4] = {{0.f, 0.f}, {0.f, 0.f}, {0.f, 0.f}, {0.f, 0.f}};
    #pragma unroll
    for (int b8 = 0; b8 < 8; b8++){
        uint2 r = rp[b8];
        v2f f0 = __builtin_amdgcn_cvt_pk_f32_fp8(r.x, false);
        v2f f1 = __builtin_amdgcn_cvt_pk_f32_fp8(r.x, true);
        v2f f2 = __builtin_amdgcn_cvt_pk_f32_fp8(r.y, false);
        v2f f3 = __builtin_amdgcn_cvt_pk_f32_fp8(r.y, true);
        float f[8] = {f0.x, f0.y, f1.x, f1.y, f2.x, f2.y, f3.x, f3.y};
        #pragma unroll
        for (int j = 0; j < 8; j++){
            v2f hcv = {f[j], f[j]};
            const v2f* wrow = (const v2f*)&sW[(b8 * 8 + j) * 8];   // broadcast b64 reads
            acc2[0] = __builtin_elementwise_fma(hcv, wrow[0], acc2[0]);
            acc2[1] = __builtin_elementwise_fma(hcv, wrow[1], acc2[1]);
            acc2[2] = __builtin_elementwise_fma(hcv, wrow[2], acc2[2]);
            acc2[3] = __builtin_elementwise_fma(hcv, wrow[3], acc2[3]);
        }
    }
    float4* xo = (float4*)(xw2 + (size_t)i * 8);
    xo[0] = make_float4(acc2[0].x, acc2[0].y, acc2[1].x, acc2[1].y);
    xo[1] = make_float4(acc2[2].x, acc2[2].y, acc2[3].x, acc2[3].y);
    float4 dv;
    dv.x = acc2[0].x * sD[0] + acc2[0].y * sD[1];
    dv.y = acc2[1].x * sD[2] + acc2[1].y * sD[3];
    dv.z = acc2[2].x * sD[4] + acc2[2].y * sD[5];
    dv.w = acc2[3].x * sD[6] + acc2[3].y * sD[7];
    *(float4*)(adv2 + (size_t)i * 4) = dv;
}

// ---- layer 2 gather: lane = (edge slot g=lane>>2 0..15, head hh=lane&3) ----
__global__ void k_l2_gather(const int2* __restrict__ offp, const int* __restrict__ csr,
                            const float* __restrict__ adv2, const float* __restrict__ xw2,
                            const float* __restrict__ b2, const float* __restrict__ as2,
                            float* __restrict__ pool, int N){
    __shared__ float lpool[8];
    int tid = threadIdx.x;
    if (tid < 8) lpool[tid] = 0.f;
    __syncthreads();
    int wid = (int)(((long)blockIdx.x * 256 + tid) >> 6);
    if (wid < N){
        int lane = tid & 63;
        int g = lane >> 2;          // edge slot 0..15
        int hh = lane & 3;          // head
        float2 a2h = *(const float2*)&as2[hh * 2];
        float advd = adv2[wid * 4 + hh];
        const char* xwh = (const char*)xw2 + hh * 8;
        v2f accv = {0.f, 0.f};
        float den = 0.f;

        auto edge = [&](int s, bool valid){
            v2f v = *(const v2f*)(xwh + ((size_t)s << 5));
            float al = v.x * a2h.x + v.y * a2h.y;
            float t = al + advd;
            float w = valid ? __expf(fmaxf(t, NEG * t)) : 0.f;
            den += w;
            v2f w2 = {w, w};
            accv = __builtin_elementwise_fma(v, w2, accv);
        };

        int2 rng = offp[wid];
        int k = rng.x, end = rng.y;
        for (; k + 32 <= end; k += 32){     // 2 batches of 16 edges in flight
            int s0 = csr[k + g], s1 = csr[k + 16 + g];
            edge(s0, true); edge(s1, true);
        }
        for (; k < end; k += 16){           // masked tail
            int e = k + g;
            bool valid = e < end;
            int s = csr[valid ? e : end - 1];
            edge(s, valid);
        }
        // reduce over edge slots (lane bits 2..5)
        #pragma unroll
        for (int m = 4; m <= 32; m <<= 1){
            accv.x += __shfl_xor(accv.x, m);
            accv.y += __shfl_xor(accv.y, m);
            den    += __shfl_xor(den, m);
        }
        if (g == 0){                         // lanes 0..3, lane hh owns head hh
            v2f v = *(const v2f*)(xwh + ((size_t)wid << 5));
            float al = v.x * a2h.x + v.y * a2h.y;
            float t = al + advd;
            float ws = __expf(fmaxf(t, NEG * t));
            den += ws;
            accv.x += ws * v.x;
            accv.y += ws * v.y;
            float inv = 1.0f / (den + 1e-16f);
            float o0 = elufast(accv.x * inv + b2[hh * 2]);
            float o1 = elufast(accv.y * inv + b2[hh * 2 + 1]);
            atomicAdd(&lpool[hh * 2], o0);
            atomicAdd(&lpool[hh * 2 + 1], o1);
        }
    }
    __syncthreads();
    if (tid < 8) atomicAdd(&pool[(blockIdx.x & 63) * 8 + tid], lpool[tid]);
}

// ---- output head: reduce 64x8 pool partials, apply mean+W+sigmoid ----
__global__ void k_final(const float* __restrict__ pool, const float* __restrict__ Wout,
                        const float* __restrict__ bout, float* __restrict__ out, float invN){
    int lane = threadIdx.x;      // 64 lanes, lane l owns slot l
    const float4* p4 = (const float4*)(pool + lane * 8);
    float4 a = p4[0], b = p4[1];
    float v[8] = {a.x, a.y, a.z, a.w, b.x, b.y, b.z, b.w};
    #pragma unroll
    for (int m = 1; m <= 32; m <<= 1){
        #pragma unroll
        for (int j = 0; j < 8; j++) v[j] += __shfl_xor(v[j], m);
    }
    if (lane == 0){
        float z = bout[0];
        #pragma unroll
        for (int j = 0; j < 8; j++) z += v[j] * invN * Wout[j];
        out[0] = 1.0f / (1.0f + __expf(-z));
    }
}

extern "C" void kernel_launch(void* const* d_in, const int* in_sizes, int n_in,
                              void* d_out, int out_size, void* d_ws, size_t ws_size,
                              hipStream_t stream){
    const float* x    = (const float*)d_in[0];
    const int*   ei   = (const int*)d_in[1];     // int32
    const float* W1   = (const float*)d_in[2];
    const float* as1  = (const float*)d_in[3];
    const float* ad1  = (const float*)d_in[4];
    const float* b1   = (const float*)d_in[5];
    const float* W2   = (const float*)d_in[6];
    const float* as2  = (const float*)d_in[7];
    const float* ad2  = (const float*)d_in[8];
    const float* b2   = (const float*)d_in[9];
    const float* Wout = (const float*)d_in[10];
    const float* bout = (const float*)d_in[11];
    float* out = (float*)d_out;

    int N = in_sizes[0] / 4;
    int E = in_sizes[1] / 2;
    const int* src = ei;
    const int* dst = ei + E;

    char* ws = (char*)d_ws;
    size_t off_b = 0;
    auto alloc = [&](size_t bytes)->void*{
        void* p = ws + off_b;
        off_b += (bytes + 255) & ~(size_t)255;
        return p;
    };
    unsigned char* xw1  = (unsigned char*)alloc((size_t)N * 64);  // fp8 e4m3
    unsigned char* h1f8 = (unsigned char*)alloc((size_t)N * 64);  // fp8 e4m3 h1
    uint2*    asvb   = (uint2*)alloc((size_t)N * 8);              // bf16x4 alpha_src
    float*    adv    = (float*)alloc((size_t)N * 4 * 4);
    float*    adv2   = (float*)alloc((size_t)N * 4 * 4);
    int*      gcnt   = (int*)alloc((size_t)MAXBUK * 4);           // per-bucket fill count
    unsigned* staged = (unsigned*)alloc((size_t)MAXBUK * CAP * 4);// slab: src | localdst<<17
    int2*     offp   = (int2*)alloc((size_t)N * 8);               // per-dst (start,end)
    int*      csr    = (int*)alloc((size_t)MAXBUK * CAP * 4);     // slab csr
    float*    xw2    = (float*)alloc((size_t)N * 8 * 4);
    float*    pool   = (float*)alloc(64 * 8 * 4);

    int nbuk = (N + BSZ - 1) / BSZ;          // 447
    int chunksz = (E + NBIN - 1) / NBIN;     // 6250 <= LSTG
    int nnodeblk = (N + 511) / 512;          // node-transform blocks (1024 thr, 2/node)
    int grid = NBIN + nnodeblk;              // interleaved roles

    hipMemsetAsync(pool, 0, 64 * 8 * 4, stream);
    hipMemsetAsync(gcnt, 0, (size_t)MAXBUK * 4, stream);

    // fused binning + node transform (roles interleaved for CU-level overlap)
    k_bin_node<<<grid, 1024, 0, stream>>>(src, dst, gcnt, staged,
                                          x, W1, as1, ad1, xw1, (unsigned*)asvb, adv,
                                          E, chunksz, nbuk, N, nnodeblk, grid);
    k_local<<<nbuk, 1024, 0, stream>>>(staged, gcnt, offp, csr, N);

    // layer 1 gather (4-deep batch + fold-reduce + distributed epilogue -> h1 fp8)
    k_l1_gather<<<(int)(((long)N * 64 + 255) / 256), 256, 0, stream>>>(
        offp, csr, asvb, adv, xw1, b1, h1f8, N);
    // dense layer-2 node transform (packed)
    k_l2_node<<<(N + 255) / 256, 256, 0, stream>>>(h1f8, W2, ad2, xw2, adv2, N);
    // layer 2 gather + fused mean pool
    k_l2_gather<<<(int)(((long)N * 64 + 255) / 256), 256, 0, stream>>>(
        offp, csr, adv2, xw2, b2, as2, pool, N);
    // head
    k_final<<<1, 64, 0, stream>>>(pool, Wout, bout, out, 1.0f / (float)N);
}